// Round 13
// baseline (806.935 us; speedup 1.0000x reference)
//
#include <hip/hip_runtime.h>
#include <stdint.h>

// ---------------- problem constants (fixed by setup_inputs) ----------------
static constexpr int NN    = 32768;   // nodes
static constexpr int NPG   = 1024;    // nodes per graph
static constexpr int EPG   = 2048;    // edges per graph
static constexpr int NGR   = 32;      // graphs
static constexpr int NF    = 8;       // filtrations
static constexpr int FEAT  = 512;
static constexpr int ODIM  = 64;
static constexpr int ETOT  = NGR * EPG;

typedef short bf16x8 __attribute__((ext_vector_type(8)));
typedef float f32x4  __attribute__((ext_vector_type(4)));

// order-preserving float -> uint key
__device__ __forceinline__ unsigned int fsort(float f) {
    unsigned int u = __float_as_uint(f);
    return (u & 0x80000000u) ? ~u : (u | 0x80000000u);
}

// split two f32 into packed bf16-hi pair and bf16-lo pair (truncation split).
__device__ __forceinline__ void split2(float a, float b, unsigned& hi, unsigned& lo) {
    unsigned ua = __float_as_uint(a), ub = __float_as_uint(b);
    hi = (ua >> 16) | (ub & 0xffff0000u);
    float ra = a - __uint_as_float(ua & 0xffff0000u);
    float rb = b - __uint_as_float(ub & 0xffff0000u);
    lo = (__float_as_uint(ra) >> 16) | (__float_as_uint(rb) & 0xffff0000u);
}

// ========== 0. W1 -> transposed, split (hi/lo bf16), tile-swizzled ==========
__global__ __launch_bounds__(256) void w1swz_k(
        const float* __restrict__ W1,
        unsigned short* __restrict__ Whi, unsigned short* __restrict__ Wlo) {
    __shared__ float T[64][65];
    const int tid = threadIdx.x;
    const int kb = blockIdx.x >> 3, cb = blockIdx.x & 7;
    const int r16 = tid >> 4, c4 = tid & 15;
#pragma unroll
    for (int p = 0; p < 4; ++p) {
        int kl = r16 + p * 16;
        *(float4*)&T[kl][c4 * 4] = *(const float4*)&W1[(size_t)(kb * 64 + kl) * FEAT + cb * 64 + c4 * 4];
    }
    __syncthreads();
    const int col_l = tid >> 2;
    const int col = cb * 64 + col_l;
    const int sw = (col + (col >> 2)) & 3;
#pragma unroll
    for (int q = 0; q < 2; ++q) {
        int ch = (tid & 3) + q * 4;
        int ktl = ch >> 2, slot = ch & 3;
        int koff = slot ^ sw;
        unsigned hi[4], lo[4];
#pragma unroll
        for (int pj = 0; pj < 4; ++pj) {
            float a = T[ktl * 32 + koff * 8 + pj * 2 + 0][col_l];
            float b = T[ktl * 32 + koff * 8 + pj * 2 + 1][col_l];
            split2(a, b, hi[pj], lo[pj]);
        }
        size_t o = (size_t)col * 512 + (size_t)kb * 64 + ktl * 32 + slot * 8;
        *(uint4*)&Whi[o] = make_uint4(hi[0], hi[1], hi[2], hi[3]);
        *(uint4*)&Wlo[o] = make_uint4(lo[0], lo[1], lo[2], lo[3]);
    }
}

// ========== 1a. split-bf16 MFMA GEMM fused with relu+b1 then @W2 ==========
__global__ __launch_bounds__(256, 2) void mfma_fv_k(
        const float* __restrict__ x, const unsigned short* __restrict__ Whi,
        const unsigned short* __restrict__ Wlo, const float* __restrict__ b1,
        const float* __restrict__ W2, float* __restrict__ fvpart) {
    __shared__ unsigned short AsHi[4096], AsLo[4096], BsHi[4096], BsLo[4096];
    __shared__ float W2s[128][8];
    __shared__ float b1s[128];

    const int tid = threadIdx.x;
    const int lane = tid & 63, wid = tid >> 6;
    const int wr = wid >> 1, wc = wid & 1;
    const int b = blockIdx.x;
    const int rb = (b & 7) * 32 + (b >> 5);
    const int cb = (b >> 3) & 3;
    const int rowBase = rb * 128, colBase = cb * 128;

    for (int i = tid; i < 1024; i += 256)
        W2s[i >> 3][i & 7] = W2[(size_t)(colBase + (i >> 3)) * NF + (i & 7)];
    if (tid < 128) b1s[tid] = b1[colBase + tid];

    const int arow = tid >> 1, ah2 = tid & 1;
    const int aswz = (arow + (arow >> 2)) & 3;
    const float* xp = x + (size_t)(rowBase + arow) * FEAT + ah2 * 16;
    const int bcol = tid >> 1;
    const size_t bsrc = (size_t)(colBase + bcol) * 512 + (size_t)(tid & 1) * 16;
    const int bdst = bcol * 32 + (tid & 1) * 16;

    f32x4 acc[4][4];
#pragma unroll
    for (int m = 0; m < 4; ++m)
#pragma unroll
        for (int n = 0; n < 4; ++n) acc[m][n] = (f32x4){0.f, 0.f, 0.f, 0.f};

    float4 av[4];
    uint4 bhv[2], blv[2];
    av[0] = ((const float4*)xp)[0]; av[1] = ((const float4*)xp)[1];
    av[2] = ((const float4*)xp)[2]; av[3] = ((const float4*)xp)[3];
    bhv[0] = *(const uint4*)(Whi + bsrc); bhv[1] = *(const uint4*)(Whi + bsrc + 8);
    blv[0] = *(const uint4*)(Wlo + bsrc); blv[1] = *(const uint4*)(Wlo + bsrc + 8);

    for (int tk = 0; tk < 16; ++tk) {
        __syncthreads();
#pragma unroll
        for (int cj = 0; cj < 2; ++cj) {
            int koff = ah2 * 2 + cj;
            int slot = koff ^ aswz;
            unsigned h0, h1, h2, h3, l0, l1, l2, l3;
            split2(av[cj * 2 + 0].x, av[cj * 2 + 0].y, h0, l0);
            split2(av[cj * 2 + 0].z, av[cj * 2 + 0].w, h1, l1);
            split2(av[cj * 2 + 1].x, av[cj * 2 + 1].y, h2, l2);
            split2(av[cj * 2 + 1].z, av[cj * 2 + 1].w, h3, l3);
            int o = arow * 32 + slot * 8;
            *(uint4*)&AsHi[o] = make_uint4(h0, h1, h2, h3);
            *(uint4*)&AsLo[o] = make_uint4(l0, l1, l2, l3);
        }
        *(uint4*)&BsHi[bdst] = bhv[0]; *(uint4*)&BsHi[bdst + 8] = bhv[1];
        *(uint4*)&BsLo[bdst] = blv[0]; *(uint4*)&BsLo[bdst + 8] = blv[1];
        if (tk < 15) {
            const float* xq = xp + (tk + 1) * 32;
            av[0] = ((const float4*)xq)[0]; av[1] = ((const float4*)xq)[1];
            av[2] = ((const float4*)xq)[2]; av[3] = ((const float4*)xq)[3];
            const unsigned short* bh = Whi + bsrc + (size_t)(tk + 1) * 32;
            const unsigned short* bl = Wlo + bsrc + (size_t)(tk + 1) * 32;
            bhv[0] = *(const uint4*)bh; bhv[1] = *(const uint4*)(bh + 8);
            blv[0] = *(const uint4*)bl; blv[1] = *(const uint4*)(bl + 8);
        }
        __syncthreads();
        bf16x8 fa[4], fb[4], f2[4];
#pragma unroll
        for (int m = 0; m < 4; ++m) {
            int r = wr * 64 + m * 16 + (lane & 15);
            int slot = (lane >> 4) ^ ((r + (r >> 2)) & 3);
            fa[m] = *(const bf16x8*)&AsHi[r * 32 + slot * 8];
        }
#pragma unroll
        for (int n = 0; n < 4; ++n) {
            int c = wc * 64 + n * 16 + (lane & 15);
            int slot = (lane >> 4) ^ ((c + (c >> 2)) & 3);
            fb[n] = *(const bf16x8*)&BsHi[c * 32 + slot * 8];
        }
#pragma unroll
        for (int m = 0; m < 4; ++m)
#pragma unroll
            for (int n = 0; n < 4; ++n)
                acc[m][n] = __builtin_amdgcn_mfma_f32_16x16x32_bf16(fa[m], fb[n], acc[m][n], 0, 0, 0);
#pragma unroll
        for (int n = 0; n < 4; ++n) {
            int c = wc * 64 + n * 16 + (lane & 15);
            int slot = (lane >> 4) ^ ((c + (c >> 2)) & 3);
            f2[n] = *(const bf16x8*)&BsLo[c * 32 + slot * 8];
        }
#pragma unroll
        for (int m = 0; m < 4; ++m)
#pragma unroll
            for (int n = 0; n < 4; ++n)
                acc[m][n] = __builtin_amdgcn_mfma_f32_16x16x32_bf16(fa[m], f2[n], acc[m][n], 0, 0, 0);
#pragma unroll
        for (int m = 0; m < 4; ++m) {
            int r = wr * 64 + m * 16 + (lane & 15);
            int slot = (lane >> 4) ^ ((r + (r >> 2)) & 3);
            f2[m] = *(const bf16x8*)&AsLo[r * 32 + slot * 8];
        }
#pragma unroll
        for (int m = 0; m < 4; ++m)
#pragma unroll
            for (int n = 0; n < 4; ++n)
                acc[m][n] = __builtin_amdgcn_mfma_f32_16x16x32_bf16(f2[m], fb[n], acc[m][n], 0, 0, 0);
    }

    const int p = cb * 2 + wc;
#pragma unroll
    for (int m = 0; m < 4; ++m) {
        float pf[4][8];
#pragma unroll
        for (int r = 0; r < 4; ++r)
#pragma unroll
            for (int j = 0; j < 8; ++j) pf[r][j] = 0.f;
#pragma unroll
        for (int n = 0; n < 4; ++n) {
            int c = wc * 64 + n * 16 + (lane & 15);
            float bc = b1s[c];
            float4 wA = *(const float4*)&W2s[c][0];
            float4 wB = *(const float4*)&W2s[c][4];
#pragma unroll
            for (int r = 0; r < 4; ++r) {
                float h = fmaxf(acc[m][n][r] + bc, 0.f);
                pf[r][0] += h * wA.x; pf[r][1] += h * wA.y; pf[r][2] += h * wA.z; pf[r][3] += h * wA.w;
                pf[r][4] += h * wB.x; pf[r][5] += h * wB.y; pf[r][6] += h * wB.z; pf[r][7] += h * wB.w;
            }
        }
#pragma unroll
        for (int mask = 1; mask <= 8; mask <<= 1)
#pragma unroll
            for (int r = 0; r < 4; ++r)
#pragma unroll
                for (int j = 0; j < 8; ++j) pf[r][j] += __shfl_xor(pf[r][j], mask);
        if ((lane & 15) == 0) {
            int rowb = rowBase + wr * 64 + m * 16 + (lane >> 4) * 4;
#pragma unroll
            for (int r = 0; r < 4; ++r) {
                *(float4*)&fvpart[(((size_t)p << 15) + rowb + r) * NF + 0] =
                    make_float4(pf[r][0], pf[r][1], pf[r][2], pf[r][3]);
                *(float4*)&fvpart[(((size_t)p << 15) + rowb + r) * NF + 4] =
                    make_float4(pf[r][4], pf[r][5], pf[r][6], pf[r][7]);
            }
        }
    }
}

// ========== 1b. fv = sum of 8 panels + b2; writes fv [N][8] and fvT [8][N] ==========
__global__ __launch_bounds__(256) void fvred_k(
        const float* __restrict__ fvpart, const float* __restrict__ b2,
        float* __restrict__ fv, float* __restrict__ fvT) {
    const int row = blockIdx.x * 256 + threadIdx.x;
    float s[8];
    *(float4*)&s[0] = *(const float4*)&b2[0];
    *(float4*)&s[4] = *(const float4*)&b2[4];
#pragma unroll
    for (int p = 0; p < 8; ++p) {
        float4 lo = *(const float4*)&fvpart[(((size_t)p << 15) + row) * NF + 0];
        float4 hi = *(const float4*)&fvpart[(((size_t)p << 15) + row) * NF + 4];
        s[0] += lo.x; s[1] += lo.y; s[2] += lo.z; s[3] += lo.w;
        s[4] += hi.x; s[5] += hi.y; s[6] += hi.z; s[7] += hi.w;
    }
    *(float4*)&fv[(size_t)row * NF + 0] = *(float4*)&s[0];
    *(float4*)&fv[(size_t)row * NF + 4] = *(float4*)&s[4];
#pragma unroll
    for (int j = 0; j < 8; ++j) fvT[(size_t)j * NN + row] = s[j];
}

// ============ 2a. per-(graph,filtration) edge key build + bitonic sort ============
__global__ __launch_bounds__(512) void uf_sort_k(
        const float* __restrict__ fvT, const int* __restrict__ ei,
        unsigned int* __restrict__ suvw) {
    __shared__ float fvl[NPG];
    __shared__ unsigned long long keys[EPG];
    __shared__ unsigned int uvw[EPG];
    const int tid = threadIdx.x;
    const int g = blockIdx.x >> 3, k = blockIdx.x & 7;

    for (int i = tid; i < NPG; i += 512) fvl[i] = fvT[(size_t)k * NN + (g << 10) + i];
    __syncthreads();
    for (int e = tid; e < EPG; e += 512) {
        int eg = g * EPG + e;
        int u = ei[eg] & (NPG - 1);
        int v = ei[ETOT + eg] & (NPG - 1);
        unsigned int fku = fsort(fvl[u]);
        unsigned int fkv = fsort(fvl[v]);
        unsigned int wfl = (fku > fkv || (fku == fkv && u >= v)) ? 1u : 0u;
        unsigned int fe = fku > fkv ? fku : fkv;
        uvw[e] = (unsigned)u | ((unsigned)v << 10) | (wfl << 20);
        keys[e] = ((unsigned long long)fe << 32) | (unsigned)e;
    }
    for (int size = 2; size <= EPG; size <<= 1) {
        for (int stride = size >> 1; stride > 0; stride >>= 1) {
            __syncthreads();
            for (int i = tid; i < EPG; i += 512) {
                int j = i ^ stride;
                if (j > i) {
                    unsigned long long a = keys[i], b = keys[j];
                    bool asc = (i & size) == 0;
                    if (asc ? (a > b) : (a < b)) { keys[i] = b; keys[j] = a; }
                }
            }
        }
    }
    __syncthreads();
    for (int i = tid; i < EPG; i += 512)
        suvw[(size_t)blockIdx.x * EPG + i] = uvw[(unsigned)(keys[i] & 0xffffffffULL)];
}

// ============ 2b. EXACT sequential union-find, windowed batched commits ============
// grid 256 blocks, 256 threads (staging + output); wave 0 executes the merge.
// node word: [fkey:32 | birth_idx:16 | parent:16]. UNION-BY-ELDER.
// Per 64-edge window: chase both roots; then iterate:
//   - alive lanes pick young root ry (larger (fkey,birth)); atomicMin-claim
//     claim[ry] with lane index (LDS, single wave -> ordered, no fences).
//   - win iff claim[ry]==lane AND lane < first blocked alive lane (PREFIX rule,
//     hardware-validated in round 10: blocked lanes can flip their young at
//     their sequential turn, so nothing after the first block may commit).
//     Winners within the prefix have distinct youngs and commute (elder
//     records invariant; young-node writes + death records disjoint).
//   - winners flush deathl + node link; writers reset their claims; remaining
//     alive lanes re-chase through fresh links and re-read records.
// ~32 alive lanes with ~distinct youngs -> whole window commits in 1-2
// iterations (vs 32 serial broadcasts in the round-12 structure).
__global__ __launch_bounds__(256) void uf_merge_k(
        const float* __restrict__ fvT, const unsigned int* __restrict__ suvw,
        float* __restrict__ dvT) {
    __shared__ float fvl[NPG];
    __shared__ unsigned long long node[NPG];
    __shared__ unsigned short deathl[NPG];
    __shared__ unsigned int se[EPG];
    __shared__ unsigned int claim[NPG];

    const int tid = threadIdx.x;
    const int g = blockIdx.x >> 3, k = blockIdx.x & 7;

    for (int i = tid; i < NPG; i += 256) {
        float val = fvT[(size_t)k * NN + (g << 10) + i];
        fvl[i] = val;
        node[i] = ((unsigned long long)fsort(val) << 32) | ((unsigned long long)(unsigned)i << 16) | (unsigned)i;
        deathl[i] = (unsigned short)i;
        claim[i] = ~0u;
    }
    for (int i = tid; i < EPG / 4; i += 256)
        ((uint4*)se)[i] = ((const uint4*)(suvw + (size_t)blockIdx.x * EPG))[i];
    __syncthreads();

    if (tid < 64) {
        const int lane = tid;
        volatile unsigned int* vn32 = (volatile unsigned int*)node;
        volatile unsigned long long* vn64 = (volatile unsigned long long*)node;
        volatile unsigned int* vcl = (volatile unsigned int*)claim;
        for (int w = 0; w < EPG / 64; ++w) {
            unsigned int pk = se[w * 64 + lane];
            int u = (int)(pk & 1023u), v = (int)((pk >> 10) & 1023u);
            int wd = ((pk >> 20) & 1u) ? u : v;       // death vertex (static)
            // initial chase with path-halving (low-dword writes keep birth bits)
            int ru = u;
            {
                unsigned int lw = vn32[ru * 2];
                int p = (int)(lw & 0xffffu);
                while (p != ru) {
                    unsigned int lw2 = vn32[p * 2];
                    int gp = (int)(lw2 & 0xffffu);
                    if (gp != p) vn32[ru * 2] = (lw & 0xffff0000u) | (unsigned)gp;
                    ru = p; lw = lw2; p = gp;
                }
            }
            int rv = v;
            {
                unsigned int lw = vn32[rv * 2];
                int p = (int)(lw & 0xffffu);
                while (p != rv) {
                    unsigned int lw2 = vn32[p * 2];
                    int gp = (int)(lw2 & 0xffffu);
                    if (gp != p) vn32[rv * 2] = (lw & 0xffff0000u) | (unsigned)gp;
                    rv = p; lw = lw2; p = gp;
                }
            }
            unsigned long long wa = vn64[ru];
            unsigned long long wb = vn64[rv];
            bool alive = (ru != rv);
            while (__ballot(alive)) {
                bool wasAlive = alive;
                int ry = 0, re = 0;
                unsigned long long wy = 0;
                if (alive) {
                    bool uY = (wa >> 16) > (wb >> 16);   // young = larger (fkey,birth)
                    ry = uY ? ru : rv; re = uY ? rv : ru;
                    wy = uY ? wa : wb;
                    atomicMin(&claim[ry], (unsigned)lane);
                }
                bool win0 = alive && (vcl[ry] == (unsigned)lane);
                unsigned long long blockedM = __ballot(alive && !win0);
                int fb = blockedM ? (int)__builtin_ctzll(blockedM) : 64;
                bool win = win0 && (lane < fb);
                if (win) {
                    deathl[(int)((wy >> 16) & 0xffffu)] = (unsigned short)wd;
                    vn64[ry] = (wy & ~0xffffULL) | (unsigned)re;
                    alive = false;
                }
                if (wasAlive) vcl[ry] = ~0u;             // writers reset claims
                if (alive) {                              // blocked: re-chase
                    int r = ru;
                    unsigned int lw = vn32[r * 2];
                    int p = (int)(lw & 0xffffu);
                    while (p != r) {
                        unsigned int lw2 = vn32[p * 2];
                        int gp = (int)(lw2 & 0xffffu);
                        if (gp != p) vn32[r * 2] = (lw & 0xffff0000u) | (unsigned)gp;
                        r = p; lw = lw2; p = gp;
                    }
                    ru = r;
                    r = rv;
                    lw = vn32[r * 2];
                    p = (int)(lw & 0xffffu);
                    while (p != r) {
                        unsigned int lw2 = vn32[p * 2];
                        int gp = (int)(lw2 & 0xffffu);
                        if (gp != p) vn32[r * 2] = (lw & 0xffff0000u) | (unsigned)gp;
                        r = p; lw = lw2; p = gp;
                    }
                    rv = r;
                    wa = vn64[ru]; wb = vn64[rv];
                    alive = (ru != rv);
                }
            }
            __builtin_amdgcn_wave_barrier();
        }
    }
    __syncthreads();
    for (int i = tid; i < NPG; i += 256)
        dvT[(size_t)k * NN + (g << 10) + i] = fvl[deathl[i]];
}

// ================= 3. h0 = relu(x0 @ W_in + b_in), x0 = interleave(fv,dvT) =================
__global__ __launch_bounds__(256, 2) void feat_k(
        const float* __restrict__ fv, const float* __restrict__ dvT,
        const float* __restrict__ W_in, const float* __restrict__ b_in,
        float* __restrict__ h0) {
    __shared__ float Ws[16][64];
    __shared__ float bs[64];
    const int tid = threadIdx.x;
    for (int i = tid; i < 1024; i += 256) Ws[i >> 6][i & 63] = W_in[i];
    if (tid < 64) bs[tid] = b_in[tid];
    __syncthreads();
    const int n = blockIdx.x * 256 + tid;
    float4 f0 = *(const float4*)&fv[(size_t)n * NF + 0];
    float4 f1 = *(const float4*)&fv[(size_t)n * NF + 4];
    float dd[8];
#pragma unroll
    for (int j = 0; j < 8; ++j) dd[j] = dvT[(size_t)j * NN + n];
    float x0[16] = { f0.x, dd[0], f0.y, dd[1], f0.z, dd[2], f0.w, dd[3],
                     f1.x, dd[4], f1.y, dd[5], f1.z, dd[6], f1.w, dd[7] };
    float out[64];
#pragma unroll
    for (int j = 0; j < 64; ++j) out[j] = bs[j];
#pragma unroll
    for (int i = 0; i < 16; ++i) {
        float a = x0[i];
#pragma unroll
        for (int j4 = 0; j4 < 16; ++j4) {
            float4 w = *(const float4*)&Ws[i][j4 * 4];
            out[j4 * 4 + 0] += a * w.x; out[j4 * 4 + 1] += a * w.y;
            out[j4 * 4 + 2] += a * w.z; out[j4 * 4 + 3] += a * w.w;
        }
    }
#pragma unroll
    for (int j4 = 0; j4 < 16; ++j4) {
        float4 o = { fmaxf(out[j4 * 4 + 0], 0.f), fmaxf(out[j4 * 4 + 1], 0.f),
                     fmaxf(out[j4 * 4 + 2], 0.f), fmaxf(out[j4 * 4 + 3], 0.f) };
        *(float4*)&h0[(size_t)n * 64 + j4 * 4] = o;
    }
}

// ================= 4. per-graph column sums of a [N,64] matrix =================
__global__ void reduce64_k(const float* __restrict__ h, float* __restrict__ s) {
    __shared__ float part[4][64];
    const int tid = threadIdx.x, g = blockIdx.x;
    const int c = tid & 63, rg = tid >> 6;
    float acc = 0.f;
    for (int r = rg; r < NPG; r += 4) acc += h[(size_t)(g * NPG + r) * 64 + c];
    part[rg][c] = acc;
    __syncthreads();
    if (tid < 64) s[g * 64 + tid] = part[0][tid] + part[1][tid] + part[2][tid] + part[3][tid];
}

// ================= 5. bias[g][j] = Gb[j] - (s[g]/1024) @ LW =================
__global__ void lam_k(const float* __restrict__ s, const float* __restrict__ LW,
                      const float* __restrict__ Gb, float* __restrict__ bias, int Fout) {
    __shared__ float sg[64];
    const int tid = threadIdx.x, g = blockIdx.x;
    if (tid < 64) sg[tid] = s[g * 64 + tid] * (1.0f / 1024.0f);
    __syncthreads();
    for (int j = tid; j < Fout; j += 256) {
        float acc = 0.f;
        for (int i = 0; i < 64; ++i) acc += sg[i] * LW[i * Fout + j];
        bias[g * Fout + j] = Gb[j] - acc;
    }
}

// ================= 6. h1 = relu(h0 @ g1W + bias1[g]) =================
__global__ __launch_bounds__(256, 2) void ds1_k(
        const float* __restrict__ h0, const float* __restrict__ g1W,
        const float* __restrict__ bias1, float* __restrict__ h1) {
    __shared__ float Ws[64][64];
    const int tid = threadIdx.x;
    for (int i = tid; i < 4096; i += 256) Ws[i >> 6][i & 63] = g1W[i];
    __syncthreads();
    const int n = blockIdx.x * 256 + tid;
    const int g = n >> 10;
    float in[64];
#pragma unroll
    for (int i4 = 0; i4 < 16; ++i4) {
        float4 t = *(const float4*)&h0[(size_t)n * 64 + i4 * 4];
        in[i4 * 4 + 0] = t.x; in[i4 * 4 + 1] = t.y; in[i4 * 4 + 2] = t.z; in[i4 * 4 + 3] = t.w;
    }
    float out[64];
#pragma unroll
    for (int j4 = 0; j4 < 16; ++j4) {
        float4 b = *(const float4*)&bias1[g * 64 + j4 * 4];
        out[j4 * 4 + 0] = b.x; out[j4 * 4 + 1] = b.y; out[j4 * 4 + 2] = b.z; out[j4 * 4 + 3] = b.w;
    }
#pragma unroll 8
    for (int i = 0; i < 64; ++i) {
        float a = in[i];
#pragma unroll
        for (int j4 = 0; j4 < 16; ++j4) {
            float4 w = *(const float4*)&Ws[i][j4 * 4];
            out[j4 * 4 + 0] += a * w.x; out[j4 * 4 + 1] += a * w.y;
            out[j4 * 4 + 2] += a * w.z; out[j4 * 4 + 3] += a * w.w;
        }
    }
#pragma unroll
    for (int j4 = 0; j4 < 16; ++j4) {
        float4 o = { fmaxf(out[j4 * 4 + 0], 0.f), fmaxf(out[j4 * 4 + 1], 0.f),
                     fmaxf(out[j4 * 4 + 2], 0.f), fmaxf(out[j4 * 4 + 3], 0.f) };
        *(float4*)&h1[(size_t)n * 64 + j4 * 4] = o;
    }
}

// ================= 7. r = relu(h1 @ g2W + bias2[g]) -> d_out =================
__global__ __launch_bounds__(256, 2) void ds2_k(
        const float* __restrict__ h1, const float* __restrict__ g2W,
        const float* __restrict__ bias2, float* __restrict__ rout) {
    __shared__ float Ht[32][68];
    __shared__ float Wt[64][68];
    const int tid = threadIdx.x;
    const int rowBase = blockIdx.x * 32;
    const int g = rowBase >> 10;
#pragma unroll
    for (int p = 0; p < 2; ++p) {
        int fid = tid + p * 256;
        int r = fid >> 4, c4 = fid & 15;
        *(float4*)&Ht[r][c4 * 4] = *(const float4*)&h1[(size_t)(rowBase + r) * 64 + c4 * 4];
    }
    const int cg = tid & 15, rg = tid >> 4;
    for (int nc = 0; nc < 8; ++nc) {
        __syncthreads();
#pragma unroll
        for (int p = 0; p < 4; ++p) {
            int fid = tid + p * 256;
            int kk = fid >> 4, c4 = fid & 15;
            *(float4*)&Wt[kk][c4 * 4] = *(const float4*)&g2W[(size_t)kk * FEAT + nc * 64 + c4 * 4];
        }
        __syncthreads();
        float a0[4] = {0.f, 0.f, 0.f, 0.f}, a1[4] = {0.f, 0.f, 0.f, 0.f};
#pragma unroll 8
        for (int kk = 0; kk < 64; ++kk) {
            float h0v = Ht[rg * 2][kk], h1v = Ht[rg * 2 + 1][kk];
            float4 w = *(const float4*)&Wt[kk][cg * 4];
            a0[0] += h0v * w.x; a0[1] += h0v * w.y; a0[2] += h0v * w.z; a0[3] += h0v * w.w;
            a1[0] += h1v * w.x; a1[1] += h1v * w.y; a1[2] += h1v * w.z; a1[3] += h1v * w.w;
        }
        float4 bv = *(const float4*)&bias2[g * FEAT + nc * 64 + cg * 4];
        int row0 = rowBase + rg * 2;
        float4 o0 = { fmaxf(a0[0] + bv.x, 0.f), fmaxf(a0[1] + bv.y, 0.f),
                      fmaxf(a0[2] + bv.z, 0.f), fmaxf(a0[3] + bv.w, 0.f) };
        float4 o1 = { fmaxf(a1[0] + bv.x, 0.f), fmaxf(a1[1] + bv.y, 0.f),
                      fmaxf(a1[2] + bv.z, 0.f), fmaxf(a1[3] + bv.w, 0.f) };
        *(float4*)&rout[(size_t)row0 * FEAT + nc * 64 + cg * 4] = o0;
        *(float4*)&rout[(size_t)(row0 + 1) * FEAT + nc * 64 + cg * 4] = o1;
    }
}

// ================= 8. BN stats =================
__global__ void bnst1_k(const float* __restrict__ r, float* __restrict__ psum, float* __restrict__ psq) {
    const int tid = threadIdx.x, b = blockIdx.x;
    const int row0 = b * 128;
    float s0 = 0.f, q0 = 0.f, s1 = 0.f, q1 = 0.f;
    for (int rr = 0; rr < 128; ++rr) {
        float a = r[(size_t)(row0 + rr) * FEAT + tid];
        float c = r[(size_t)(row0 + rr) * FEAT + 256 + tid];
        s0 += a; q0 += a * a; s1 += c; q1 += c * c;
    }
    psum[b * FEAT + tid] = s0; psum[b * FEAT + 256 + tid] = s1;
    psq [b * FEAT + tid] = q0; psq [b * FEAT + 256 + tid] = q1;
}

__global__ void bnst2_k(const float* __restrict__ psum, const float* __restrict__ psq,
                        const float* __restrict__ gamma, const float* __restrict__ beta,
                        float* __restrict__ scsh) {
    const int tid = threadIdx.x;
    for (int c = tid; c < FEAT; c += 256) {
        float s = 0.f, q = 0.f;
        for (int b = 0; b < 256; ++b) { s += psum[b * FEAT + c]; q += psq[b * FEAT + c]; }
        float mu = s * (1.0f / (float)NN);
        float var = q * (1.0f / (float)NN) - mu * mu;
        float sc = gamma[c] * rsqrtf(var + 1e-5f);
        scsh[c] = sc;
        scsh[FEAT + c] = beta[c] - mu * sc;
    }
}

// ================= 9. out = x + r*scale + shift (in-place on d_out) =================
__global__ void final_k(const float* __restrict__ x, const float* __restrict__ scsh,
                        float* __restrict__ out) {
    const int total4 = NN * (FEAT / 4);
    for (int idx = blockIdx.x * 256 + threadIdx.x; idx < total4; idx += 2048 * 256) {
        int col4 = idx & (FEAT / 4 - 1);
        float4 rv = *(float4*)&out[(size_t)idx * 4];
        float4 xv = *(const float4*)&x[(size_t)idx * 4];
        float4 sc = *(const float4*)&scsh[col4 * 4];
        float4 sh = *(const float4*)&scsh[FEAT + col4 * 4];
        float4 o = { xv.x + rv.x * sc.x + sh.x, xv.y + rv.y * sc.y + sh.y,
                     xv.z + rv.z * sc.z + sh.z, xv.w + rv.w * sc.w + sh.w };
        *(float4*)&out[(size_t)idx * 4] = o;
    }
}

// =============================== launcher ===============================
extern "C" void kernel_launch(void* const* d_in, const int* in_sizes, int n_in,
                              void* d_out, int out_size, void* d_ws, size_t ws_size,
                              hipStream_t stream) {
    const float* x     = (const float*)d_in[0];
    const int*   ei    = (const int*)d_in[1];
    const float* W1    = (const float*)d_in[5];
    const float* b1    = (const float*)d_in[6];
    const float* W2    = (const float*)d_in[7];
    const float* b2    = (const float*)d_in[8];
    const float* W_in  = (const float*)d_in[9];
    const float* b_in  = (const float*)d_in[10];
    const float* g1W   = (const float*)d_in[11];
    const float* g1b   = (const float*)d_in[12];
    const float* l1W   = (const float*)d_in[13];
    const float* g2W   = (const float*)d_in[14];
    const float* g2b   = (const float*)d_in[15];
    const float* l2W   = (const float*)d_in[16];
    const float* gamma = (const float*)d_in[17];
    const float* beta  = (const float*)d_in[18];
    float* out = (float*)d_out;
    float* ws  = (float*)d_ws;

    float* fv    = ws;                 // [0, 262144)
    float* dvT   = ws + 262144;        // [262144, 524288)  (col-major [8][N])
    float* h0    = ws + 524288;        // [524288, 2621440)
    float* h1    = ws + 2621440;       // [2621440, 4718592)
    unsigned short* W1hi = (unsigned short*)(ws + 262144);  // aliases dvT (written later)
    unsigned short* W1lo = (unsigned short*)(ws + 393216);
    float*        fvpart = ws + 524288;                     // aliases h0 (written later)
    float*        fvT  = ws + 2621440;                      // aliases h1 (written later)
    unsigned int* suvw = (unsigned int*)(ws + 2883584);
    float* s1    = ws + 4718592;
    float* bias1 = ws + 4720640;
    float* s2    = ws + 4722688;
    float* bias2 = ws + 4724736;
    float* psum  = ws + 4741120;
    float* psq   = ws + 4872192;
    float* scsh  = ws + 5003264;

    hipLaunchKernelGGL(w1swz_k,    dim3(64),   dim3(256), 0, stream, W1, W1hi, W1lo);
    hipLaunchKernelGGL(mfma_fv_k,  dim3(1024), dim3(256), 0, stream, x, W1hi, W1lo, b1, W2, fvpart);
    hipLaunchKernelGGL(fvred_k,    dim3(128),  dim3(256), 0, stream, fvpart, b2, fv, fvT);
    hipLaunchKernelGGL(uf_sort_k,  dim3(256),  dim3(512), 0, stream, fvT, ei, suvw);
    hipLaunchKernelGGL(uf_merge_k, dim3(256),  dim3(256), 0, stream, fvT, suvw, dvT);
    hipLaunchKernelGGL(feat_k,     dim3(128),  dim3(256), 0, stream, fv, dvT, W_in, b_in, h0);
    hipLaunchKernelGGL(reduce64_k, dim3(32),   dim3(256), 0, stream, h0, s1);
    hipLaunchKernelGGL(lam_k,      dim3(32),   dim3(256), 0, stream, s1, l1W, g1b, bias1, 64);
    hipLaunchKernelGGL(ds1_k,      dim3(128),  dim3(256), 0, stream, h0, g1W, bias1, h1);
    hipLaunchKernelGGL(reduce64_k, dim3(32),   dim3(256), 0, stream, h1, s2);
    hipLaunchKernelGGL(lam_k,      dim3(32),   dim3(256), 0, stream, s2, l2W, g2b, bias2, 512);
    hipLaunchKernelGGL(ds2_k,      dim3(1024), dim3(256), 0, stream, h1, g2W, bias2, out);
    hipLaunchKernelGGL(bnst1_k,    dim3(256),  dim3(256), 0, stream, out, psum, psq);
    hipLaunchKernelGGL(bnst2_k,    dim3(1),    dim3(256), 0, stream, psum, psq, gamma, beta, scsh);
    hipLaunchKernelGGL(final_k,    dim3(2048), dim3(256), 0, stream, x, scsh, out);
}

// Round 14
// 650.715 us; speedup vs baseline: 1.2401x; 1.2401x over previous
//
#include <hip/hip_runtime.h>
#include <stdint.h>

// ---------------- problem constants (fixed by setup_inputs) ----------------
static constexpr int NN    = 32768;   // nodes
static constexpr int NPG   = 1024;    // nodes per graph
static constexpr int EPG   = 2048;    // edges per graph
static constexpr int NGR   = 32;      // graphs
static constexpr int NF    = 8;       // filtrations
static constexpr int FEAT  = 512;
static constexpr int ODIM  = 64;
static constexpr int ETOT  = NGR * EPG;

typedef short bf16x8 __attribute__((ext_vector_type(8)));
typedef float f32x4  __attribute__((ext_vector_type(4)));

// order-preserving float -> uint key
__device__ __forceinline__ unsigned int fsort(float f) {
    unsigned int u = __float_as_uint(f);
    return (u & 0x80000000u) ? ~u : (u | 0x80000000u);
}

// split two f32 into packed bf16-hi pair and bf16-lo pair (truncation split).
__device__ __forceinline__ void split2(float a, float b, unsigned& hi, unsigned& lo) {
    unsigned ua = __float_as_uint(a), ub = __float_as_uint(b);
    hi = (ua >> 16) | (ub & 0xffff0000u);
    float ra = a - __uint_as_float(ua & 0xffff0000u);
    float rb = b - __uint_as_float(ub & 0xffff0000u);
    lo = (__float_as_uint(ra) >> 16) | (__float_as_uint(rb) & 0xffff0000u);
}

// ========== 0. W1 -> transposed, split (hi/lo bf16), tile-swizzled ==========
__global__ __launch_bounds__(256) void w1swz_k(
        const float* __restrict__ W1,
        unsigned short* __restrict__ Whi, unsigned short* __restrict__ Wlo) {
    __shared__ float T[64][65];
    const int tid = threadIdx.x;
    const int kb = blockIdx.x >> 3, cb = blockIdx.x & 7;
    const int r16 = tid >> 4, c4 = tid & 15;
#pragma unroll
    for (int p = 0; p < 4; ++p) {
        int kl = r16 + p * 16;
        *(float4*)&T[kl][c4 * 4] = *(const float4*)&W1[(size_t)(kb * 64 + kl) * FEAT + cb * 64 + c4 * 4];
    }
    __syncthreads();
    const int col_l = tid >> 2;
    const int col = cb * 64 + col_l;
    const int sw = (col + (col >> 2)) & 3;
#pragma unroll
    for (int q = 0; q < 2; ++q) {
        int ch = (tid & 3) + q * 4;
        int ktl = ch >> 2, slot = ch & 3;
        int koff = slot ^ sw;
        unsigned hi[4], lo[4];
#pragma unroll
        for (int pj = 0; pj < 4; ++pj) {
            float a = T[ktl * 32 + koff * 8 + pj * 2 + 0][col_l];
            float b = T[ktl * 32 + koff * 8 + pj * 2 + 1][col_l];
            split2(a, b, hi[pj], lo[pj]);
        }
        size_t o = (size_t)col * 512 + (size_t)kb * 64 + ktl * 32 + slot * 8;
        *(uint4*)&Whi[o] = make_uint4(hi[0], hi[1], hi[2], hi[3]);
        *(uint4*)&Wlo[o] = make_uint4(lo[0], lo[1], lo[2], lo[3]);
    }
}

// ========== 1a. split-bf16 MFMA GEMM fused with relu+b1 then @W2 ==========
__global__ __launch_bounds__(256, 2) void mfma_fv_k(
        const float* __restrict__ x, const unsigned short* __restrict__ Whi,
        const unsigned short* __restrict__ Wlo, const float* __restrict__ b1,
        const float* __restrict__ W2, float* __restrict__ fvpart) {
    __shared__ unsigned short AsHi[4096], AsLo[4096], BsHi[4096], BsLo[4096];
    __shared__ float W2s[128][8];
    __shared__ float b1s[128];

    const int tid = threadIdx.x;
    const int lane = tid & 63, wid = tid >> 6;
    const int wr = wid >> 1, wc = wid & 1;
    const int b = blockIdx.x;
    const int rb = (b & 7) * 32 + (b >> 5);
    const int cb = (b >> 3) & 3;
    const int rowBase = rb * 128, colBase = cb * 128;

    for (int i = tid; i < 1024; i += 256)
        W2s[i >> 3][i & 7] = W2[(size_t)(colBase + (i >> 3)) * NF + (i & 7)];
    if (tid < 128) b1s[tid] = b1[colBase + tid];

    const int arow = tid >> 1, ah2 = tid & 1;
    const int aswz = (arow + (arow >> 2)) & 3;
    const float* xp = x + (size_t)(rowBase + arow) * FEAT + ah2 * 16;
    const int bcol = tid >> 1;
    const size_t bsrc = (size_t)(colBase + bcol) * 512 + (size_t)(tid & 1) * 16;
    const int bdst = bcol * 32 + (tid & 1) * 16;

    f32x4 acc[4][4];
#pragma unroll
    for (int m = 0; m < 4; ++m)
#pragma unroll
        for (int n = 0; n < 4; ++n) acc[m][n] = (f32x4){0.f, 0.f, 0.f, 0.f};

    float4 av[4];
    uint4 bhv[2], blv[2];
    av[0] = ((const float4*)xp)[0]; av[1] = ((const float4*)xp)[1];
    av[2] = ((const float4*)xp)[2]; av[3] = ((const float4*)xp)[3];
    bhv[0] = *(const uint4*)(Whi + bsrc); bhv[1] = *(const uint4*)(Whi + bsrc + 8);
    blv[0] = *(const uint4*)(Wlo + bsrc); blv[1] = *(const uint4*)(Wlo + bsrc + 8);

    for (int tk = 0; tk < 16; ++tk) {
        __syncthreads();
#pragma unroll
        for (int cj = 0; cj < 2; ++cj) {
            int koff = ah2 * 2 + cj;
            int slot = koff ^ aswz;
            unsigned h0, h1, h2, h3, l0, l1, l2, l3;
            split2(av[cj * 2 + 0].x, av[cj * 2 + 0].y, h0, l0);
            split2(av[cj * 2 + 0].z, av[cj * 2 + 0].w, h1, l1);
            split2(av[cj * 2 + 1].x, av[cj * 2 + 1].y, h2, l2);
            split2(av[cj * 2 + 1].z, av[cj * 2 + 1].w, h3, l3);
            int o = arow * 32 + slot * 8;
            *(uint4*)&AsHi[o] = make_uint4(h0, h1, h2, h3);
            *(uint4*)&AsLo[o] = make_uint4(l0, l1, l2, l3);
        }
        *(uint4*)&BsHi[bdst] = bhv[0]; *(uint4*)&BsHi[bdst + 8] = bhv[1];
        *(uint4*)&BsLo[bdst] = blv[0]; *(uint4*)&BsLo[bdst + 8] = blv[1];
        if (tk < 15) {
            const float* xq = xp + (tk + 1) * 32;
            av[0] = ((const float4*)xq)[0]; av[1] = ((const float4*)xq)[1];
            av[2] = ((const float4*)xq)[2]; av[3] = ((const float4*)xq)[3];
            const unsigned short* bh = Whi + bsrc + (size_t)(tk + 1) * 32;
            const unsigned short* bl = Wlo + bsrc + (size_t)(tk + 1) * 32;
            bhv[0] = *(const uint4*)bh; bhv[1] = *(const uint4*)(bh + 8);
            blv[0] = *(const uint4*)bl; blv[1] = *(const uint4*)(bl + 8);
        }
        __syncthreads();
        bf16x8 fa[4], fb[4], f2[4];
#pragma unroll
        for (int m = 0; m < 4; ++m) {
            int r = wr * 64 + m * 16 + (lane & 15);
            int slot = (lane >> 4) ^ ((r + (r >> 2)) & 3);
            fa[m] = *(const bf16x8*)&AsHi[r * 32 + slot * 8];
        }
#pragma unroll
        for (int n = 0; n < 4; ++n) {
            int c = wc * 64 + n * 16 + (lane & 15);
            int slot = (lane >> 4) ^ ((c + (c >> 2)) & 3);
            fb[n] = *(const bf16x8*)&BsHi[c * 32 + slot * 8];
        }
#pragma unroll
        for (int m = 0; m < 4; ++m)
#pragma unroll
            for (int n = 0; n < 4; ++n)
                acc[m][n] = __builtin_amdgcn_mfma_f32_16x16x32_bf16(fa[m], fb[n], acc[m][n], 0, 0, 0);
#pragma unroll
        for (int n = 0; n < 4; ++n) {
            int c = wc * 64 + n * 16 + (lane & 15);
            int slot = (lane >> 4) ^ ((c + (c >> 2)) & 3);
            f2[n] = *(const bf16x8*)&BsLo[c * 32 + slot * 8];
        }
#pragma unroll
        for (int m = 0; m < 4; ++m)
#pragma unroll
            for (int n = 0; n < 4; ++n)
                acc[m][n] = __builtin_amdgcn_mfma_f32_16x16x32_bf16(fa[m], f2[n], acc[m][n], 0, 0, 0);
#pragma unroll
        for (int m = 0; m < 4; ++m) {
            int r = wr * 64 + m * 16 + (lane & 15);
            int slot = (lane >> 4) ^ ((r + (r >> 2)) & 3);
            f2[m] = *(const bf16x8*)&AsLo[r * 32 + slot * 8];
        }
#pragma unroll
        for (int m = 0; m < 4; ++m)
#pragma unroll
            for (int n = 0; n < 4; ++n)
                acc[m][n] = __builtin_amdgcn_mfma_f32_16x16x32_bf16(f2[m], fb[n], acc[m][n], 0, 0, 0);
    }

    const int p = cb * 2 + wc;
#pragma unroll
    for (int m = 0; m < 4; ++m) {
        float pf[4][8];
#pragma unroll
        for (int r = 0; r < 4; ++r)
#pragma unroll
            for (int j = 0; j < 8; ++j) pf[r][j] = 0.f;
#pragma unroll
        for (int n = 0; n < 4; ++n) {
            int c = wc * 64 + n * 16 + (lane & 15);
            float bc = b1s[c];
            float4 wA = *(const float4*)&W2s[c][0];
            float4 wB = *(const float4*)&W2s[c][4];
#pragma unroll
            for (int r = 0; r < 4; ++r) {
                float h = fmaxf(acc[m][n][r] + bc, 0.f);
                pf[r][0] += h * wA.x; pf[r][1] += h * wA.y; pf[r][2] += h * wA.z; pf[r][3] += h * wA.w;
                pf[r][4] += h * wB.x; pf[r][5] += h * wB.y; pf[r][6] += h * wB.z; pf[r][7] += h * wB.w;
            }
        }
#pragma unroll
        for (int mask = 1; mask <= 8; mask <<= 1)
#pragma unroll
            for (int r = 0; r < 4; ++r)
#pragma unroll
                for (int j = 0; j < 8; ++j) pf[r][j] += __shfl_xor(pf[r][j], mask);
        if ((lane & 15) == 0) {
            int rowb = rowBase + wr * 64 + m * 16 + (lane >> 4) * 4;
#pragma unroll
            for (int r = 0; r < 4; ++r) {
                *(float4*)&fvpart[(((size_t)p << 15) + rowb + r) * NF + 0] =
                    make_float4(pf[r][0], pf[r][1], pf[r][2], pf[r][3]);
                *(float4*)&fvpart[(((size_t)p << 15) + rowb + r) * NF + 4] =
                    make_float4(pf[r][4], pf[r][5], pf[r][6], pf[r][7]);
            }
        }
    }
}

// ========== 1b. fv = sum of 8 panels + b2; writes fv [N][8] and fvT [8][N] ==========
__global__ __launch_bounds__(256) void fvred_k(
        const float* __restrict__ fvpart, const float* __restrict__ b2,
        float* __restrict__ fv, float* __restrict__ fvT) {
    const int row = blockIdx.x * 256 + threadIdx.x;
    float s[8];
    *(float4*)&s[0] = *(const float4*)&b2[0];
    *(float4*)&s[4] = *(const float4*)&b2[4];
#pragma unroll
    for (int p = 0; p < 8; ++p) {
        float4 lo = *(const float4*)&fvpart[(((size_t)p << 15) + row) * NF + 0];
        float4 hi = *(const float4*)&fvpart[(((size_t)p << 15) + row) * NF + 4];
        s[0] += lo.x; s[1] += lo.y; s[2] += lo.z; s[3] += lo.w;
        s[4] += hi.x; s[5] += hi.y; s[6] += hi.z; s[7] += hi.w;
    }
    *(float4*)&fv[(size_t)row * NF + 0] = *(float4*)&s[0];
    *(float4*)&fv[(size_t)row * NF + 4] = *(float4*)&s[4];
#pragma unroll
    for (int j = 0; j < 8; ++j) fvT[(size_t)j * NN + row] = s[j];
}

// ============ 2a. per-(graph,filtration) edge key build + bitonic sort ============
__global__ __launch_bounds__(512) void uf_sort_k(
        const float* __restrict__ fvT, const int* __restrict__ ei,
        unsigned int* __restrict__ suvw) {
    __shared__ float fvl[NPG];
    __shared__ unsigned long long keys[EPG];
    __shared__ unsigned int uvw[EPG];
    const int tid = threadIdx.x;
    const int g = blockIdx.x >> 3, k = blockIdx.x & 7;

    for (int i = tid; i < NPG; i += 512) fvl[i] = fvT[(size_t)k * NN + (g << 10) + i];
    __syncthreads();
    for (int e = tid; e < EPG; e += 512) {
        int eg = g * EPG + e;
        int u = ei[eg] & (NPG - 1);
        int v = ei[ETOT + eg] & (NPG - 1);
        unsigned int fku = fsort(fvl[u]);
        unsigned int fkv = fsort(fvl[v]);
        unsigned int wfl = (fku > fkv || (fku == fkv && u >= v)) ? 1u : 0u;
        unsigned int fe = fku > fkv ? fku : fkv;
        uvw[e] = (unsigned)u | ((unsigned)v << 10) | (wfl << 20);
        keys[e] = ((unsigned long long)fe << 32) | (unsigned)e;
    }
    for (int size = 2; size <= EPG; size <<= 1) {
        for (int stride = size >> 1; stride > 0; stride >>= 1) {
            __syncthreads();
            for (int i = tid; i < EPG; i += 512) {
                int j = i ^ stride;
                if (j > i) {
                    unsigned long long a = keys[i], b = keys[j];
                    bool asc = (i & size) == 0;
                    if (asc ? (a > b) : (a < b)) { keys[i] = b; keys[j] = a; }
                }
            }
        }
    }
    __syncthreads();
    for (int i = tid; i < EPG; i += 512)
        suvw[(size_t)blockIdx.x * EPG + i] = uvw[(unsigned)(keys[i] & 0xffffffffULL)];
}

// ============ 2b. EXACT sequential union-find at wave speed ============
// grid 256 blocks, 256 threads (staging + output); wave 0 executes the merge.
// node word: [fkey:32 | birth_idx:16 | parent:16]. UNION-BY-ELDER: young root
// links under elder root; elder root's record is invariant.
// Round-12 structure (serial ballot-commit, LDS writes deferred to window
// end) with the broadcast cut from 6 words to 3: lane li decides elder/young
// LOCALLY and broadcasts only {rY|rE<<10, wE_lo, wE_hi}. Other lanes patch
// root rY->rE and record->wE (elder record is invariant; if rE is later
// youngified, that commit re-patches). Death/node writes stay li-local.
__global__ __launch_bounds__(256) void uf_merge_k(
        const float* __restrict__ fvT, const unsigned int* __restrict__ suvw,
        float* __restrict__ dvT) {
    __shared__ float fvl[NPG];
    __shared__ unsigned long long node[NPG];
    __shared__ unsigned short deathl[NPG];
    __shared__ unsigned int se[EPG];

    const int tid = threadIdx.x;
    const int g = blockIdx.x >> 3, k = blockIdx.x & 7;

    for (int i = tid; i < NPG; i += 256) {
        float val = fvT[(size_t)k * NN + (g << 10) + i];
        fvl[i] = val;
        node[i] = ((unsigned long long)fsort(val) << 32) | ((unsigned long long)(unsigned)i << 16) | (unsigned)i;
        deathl[i] = (unsigned short)i;
    }
    for (int i = tid; i < EPG / 4; i += 256)
        ((uint4*)se)[i] = ((const uint4*)(suvw + (size_t)blockIdx.x * EPG))[i];
    __syncthreads();

    if (tid < 64) {
        const int lane = tid;
        volatile unsigned int* vn32 = (volatile unsigned int*)node;
        volatile unsigned long long* vn64 = (volatile unsigned long long*)node;
        for (int w = 0; w < EPG / 64; ++w) {
            unsigned int pk = se[w * 64 + lane];
            int u = (int)(pk & 1023u), v = (int)((pk >> 10) & 1023u);
            int wd = ((pk >> 20) & 1u) ? u : v;       // death vertex (static)
            // chase with path-halving (low-dword writes preserve birth bits)
            int ru = u;
            {
                unsigned int lw = vn32[ru * 2];
                int p = (int)(lw & 0xffffu);
                while (p != ru) {
                    unsigned int lw2 = vn32[p * 2];
                    int gp = (int)(lw2 & 0xffffu);
                    if (gp != p) vn32[ru * 2] = (lw & 0xffff0000u) | (unsigned)gp;
                    ru = p; lw = lw2; p = gp;
                }
            }
            int rv = v;
            {
                unsigned int lw = vn32[rv * 2];
                int p = (int)(lw & 0xffffu);
                while (p != rv) {
                    unsigned int lw2 = vn32[p * 2];
                    int gp = (int)(lw2 & 0xffffu);
                    if (gp != p) vn32[rv * 2] = (lw & 0xffff0000u) | (unsigned)gp;
                    rv = p; lw = lw2; p = gp;
                }
            }
            unsigned long long wa = vn64[ru];
            unsigned long long wb = vn64[rv];
            bool aliveF = (ru != rv);
            bool committed = false;
            int cY = 0, cE = 0;
            unsigned long long cW = 0;
            unsigned long long mask = __ballot(aliveF);
            while (mask) {
                int li = (int)__builtin_ctzll(mask);   // lowest alive lane = sorted order
                // each lane computes its own elder/young split (cheap VALU);
                // only lane li's packed values are broadcast (3 shfls total).
                bool uE = (wa >> 16) <= (wb >> 16);
                int rE_l = uE ? ru : rv;
                int rY_l = uE ? rv : ru;
                unsigned long long wE_l = uE ? wa : wb;
                unsigned long long wY_l = uE ? wb : wa;
                unsigned pk2 = (unsigned)rY_l | ((unsigned)rE_l << 10);
                unsigned bpk = __shfl(pk2, li);
                unsigned belo = __shfl((unsigned)wE_l, li);
                unsigned behi = __shfl((unsigned)(wE_l >> 32), li);
                unsigned long long bwE = ((unsigned long long)behi << 32) | belo;
                int brY = (int)(bpk & 1023u), brE = (int)((bpk >> 10) & 1023u);
                if (lane == li) { committed = true; cY = rY_l; cE = rE_l; cW = wY_l; }
                if (ru == brY) { ru = brE; wa = bwE; }
                if (rv == brY) { rv = brE; wb = bwE; }
                aliveF = aliveF && (lane > li) && (ru != rv);
                mask = __ballot(aliveF);
            }
            // flush: disjoint young-root links + death records
            if (committed) {
                deathl[(int)((cW >> 16) & 0xffffu)] = (unsigned short)wd;
                vn64[cY] = (cW & ~0xffffULL) | (unsigned)cE;
            }
            __builtin_amdgcn_wave_barrier();
        }
    }
    __syncthreads();
    for (int i = tid; i < NPG; i += 256)
        dvT[(size_t)k * NN + (g << 10) + i] = fvl[deathl[i]];
}

// ================= 3. h0 = relu(x0 @ W_in + b_in), x0 = interleave(fv,dvT) =================
__global__ __launch_bounds__(256, 2) void feat_k(
        const float* __restrict__ fv, const float* __restrict__ dvT,
        const float* __restrict__ W_in, const float* __restrict__ b_in,
        float* __restrict__ h0) {
    __shared__ float Ws[16][64];
    __shared__ float bs[64];
    const int tid = threadIdx.x;
    for (int i = tid; i < 1024; i += 256) Ws[i >> 6][i & 63] = W_in[i];
    if (tid < 64) bs[tid] = b_in[tid];
    __syncthreads();
    const int n = blockIdx.x * 256 + tid;
    float4 f0 = *(const float4*)&fv[(size_t)n * NF + 0];
    float4 f1 = *(const float4*)&fv[(size_t)n * NF + 4];
    float dd[8];
#pragma unroll
    for (int j = 0; j < 8; ++j) dd[j] = dvT[(size_t)j * NN + n];
    float x0[16] = { f0.x, dd[0], f0.y, dd[1], f0.z, dd[2], f0.w, dd[3],
                     f1.x, dd[4], f1.y, dd[5], f1.z, dd[6], f1.w, dd[7] };
    float out[64];
#pragma unroll
    for (int j = 0; j < 64; ++j) out[j] = bs[j];
#pragma unroll
    for (int i = 0; i < 16; ++i) {
        float a = x0[i];
#pragma unroll
        for (int j4 = 0; j4 < 16; ++j4) {
            float4 w = *(const float4*)&Ws[i][j4 * 4];
            out[j4 * 4 + 0] += a * w.x; out[j4 * 4 + 1] += a * w.y;
            out[j4 * 4 + 2] += a * w.z; out[j4 * 4 + 3] += a * w.w;
        }
    }
#pragma unroll
    for (int j4 = 0; j4 < 16; ++j4) {
        float4 o = { fmaxf(out[j4 * 4 + 0], 0.f), fmaxf(out[j4 * 4 + 1], 0.f),
                     fmaxf(out[j4 * 4 + 2], 0.f), fmaxf(out[j4 * 4 + 3], 0.f) };
        *(float4*)&h0[(size_t)n * 64 + j4 * 4] = o;
    }
}

// ================= 4. per-graph column sums of a [N,64] matrix =================
__global__ void reduce64_k(const float* __restrict__ h, float* __restrict__ s) {
    __shared__ float part[4][64];
    const int tid = threadIdx.x, g = blockIdx.x;
    const int c = tid & 63, rg = tid >> 6;
    float acc = 0.f;
    for (int r = rg; r < NPG; r += 4) acc += h[(size_t)(g * NPG + r) * 64 + c];
    part[rg][c] = acc;
    __syncthreads();
    if (tid < 64) s[g * 64 + tid] = part[0][tid] + part[1][tid] + part[2][tid] + part[3][tid];
}

// ================= 5. bias[g][j] = Gb[j] - (s[g]/1024) @ LW =================
__global__ void lam_k(const float* __restrict__ s, const float* __restrict__ LW,
                      const float* __restrict__ Gb, float* __restrict__ bias, int Fout) {
    __shared__ float sg[64];
    const int tid = threadIdx.x, g = blockIdx.x;
    if (tid < 64) sg[tid] = s[g * 64 + tid] * (1.0f / 1024.0f);
    __syncthreads();
    for (int j = tid; j < Fout; j += 256) {
        float acc = 0.f;
        for (int i = 0; i < 64; ++i) acc += sg[i] * LW[i * Fout + j];
        bias[g * Fout + j] = Gb[j] - acc;
    }
}

// ================= 6. h1 = relu(h0 @ g1W + bias1[g]) =================
__global__ __launch_bounds__(256, 2) void ds1_k(
        const float* __restrict__ h0, const float* __restrict__ g1W,
        const float* __restrict__ bias1, float* __restrict__ h1) {
    __shared__ float Ws[64][64];
    const int tid = threadIdx.x;
    for (int i = tid; i < 4096; i += 256) Ws[i >> 6][i & 63] = g1W[i];
    __syncthreads();
    const int n = blockIdx.x * 256 + tid;
    const int g = n >> 10;
    float in[64];
#pragma unroll
    for (int i4 = 0; i4 < 16; ++i4) {
        float4 t = *(const float4*)&h0[(size_t)n * 64 + i4 * 4];
        in[i4 * 4 + 0] = t.x; in[i4 * 4 + 1] = t.y; in[i4 * 4 + 2] = t.z; in[i4 * 4 + 3] = t.w;
    }
    float out[64];
#pragma unroll
    for (int j4 = 0; j4 < 16; ++j4) {
        float4 b = *(const float4*)&bias1[g * 64 + j4 * 4];
        out[j4 * 4 + 0] = b.x; out[j4 * 4 + 1] = b.y; out[j4 * 4 + 2] = b.z; out[j4 * 4 + 3] = b.w;
    }
#pragma unroll 8
    for (int i = 0; i < 64; ++i) {
        float a = in[i];
#pragma unroll
        for (int j4 = 0; j4 < 16; ++j4) {
            float4 w = *(const float4*)&Ws[i][j4 * 4];
            out[j4 * 4 + 0] += a * w.x; out[j4 * 4 + 1] += a * w.y;
            out[j4 * 4 + 2] += a * w.z; out[j4 * 4 + 3] += a * w.w;
        }
    }
#pragma unroll
    for (int j4 = 0; j4 < 16; ++j4) {
        float4 o = { fmaxf(out[j4 * 4 + 0], 0.f), fmaxf(out[j4 * 4 + 1], 0.f),
                     fmaxf(out[j4 * 4 + 2], 0.f), fmaxf(out[j4 * 4 + 3], 0.f) };
        *(float4*)&h1[(size_t)n * 64 + j4 * 4] = o;
    }
}

// ================= 7. r = relu(h1 @ g2W + bias2[g]) -> d_out =================
__global__ __launch_bounds__(256, 2) void ds2_k(
        const float* __restrict__ h1, const float* __restrict__ g2W,
        const float* __restrict__ bias2, float* __restrict__ rout) {
    __shared__ float Ht[32][68];
    __shared__ float Wt[64][68];
    const int tid = threadIdx.x;
    const int rowBase = blockIdx.x * 32;
    const int g = rowBase >> 10;
#pragma unroll
    for (int p = 0; p < 2; ++p) {
        int fid = tid + p * 256;
        int r = fid >> 4, c4 = fid & 15;
        *(float4*)&Ht[r][c4 * 4] = *(const float4*)&h1[(size_t)(rowBase + r) * 64 + c4 * 4];
    }
    const int cg = tid & 15, rg = tid >> 4;
    for (int nc = 0; nc < 8; ++nc) {
        __syncthreads();
#pragma unroll
        for (int p = 0; p < 4; ++p) {
            int fid = tid + p * 256;
            int kk = fid >> 4, c4 = fid & 15;
            *(float4*)&Wt[kk][c4 * 4] = *(const float4*)&g2W[(size_t)kk * FEAT + nc * 64 + c4 * 4];
        }
        __syncthreads();
        float a0[4] = {0.f, 0.f, 0.f, 0.f}, a1[4] = {0.f, 0.f, 0.f, 0.f};
#pragma unroll 8
        for (int kk = 0; kk < 64; ++kk) {
            float h0v = Ht[rg * 2][kk], h1v = Ht[rg * 2 + 1][kk];
            float4 w = *(const float4*)&Wt[kk][cg * 4];
            a0[0] += h0v * w.x; a0[1] += h0v * w.y; a0[2] += h0v * w.z; a0[3] += h0v * w.w;
            a1[0] += h1v * w.x; a1[1] += h1v * w.y; a1[2] += h1v * w.z; a1[3] += h1v * w.w;
        }
        float4 bv = *(const float4*)&bias2[g * FEAT + nc * 64 + cg * 4];
        int row0 = rowBase + rg * 2;
        float4 o0 = { fmaxf(a0[0] + bv.x, 0.f), fmaxf(a0[1] + bv.y, 0.f),
                      fmaxf(a0[2] + bv.z, 0.f), fmaxf(a0[3] + bv.w, 0.f) };
        float4 o1 = { fmaxf(a1[0] + bv.x, 0.f), fmaxf(a1[1] + bv.y, 0.f),
                      fmaxf(a1[2] + bv.z, 0.f), fmaxf(a1[3] + bv.w, 0.f) };
        *(float4*)&rout[(size_t)row0 * FEAT + nc * 64 + cg * 4] = o0;
        *(float4*)&rout[(size_t)(row0 + 1) * FEAT + nc * 64 + cg * 4] = o1;
    }
}

// ================= 8. BN stats =================
__global__ void bnst1_k(const float* __restrict__ r, float* __restrict__ psum, float* __restrict__ psq) {
    const int tid = threadIdx.x, b = blockIdx.x;
    const int row0 = b * 128;
    float s0 = 0.f, q0 = 0.f, s1 = 0.f, q1 = 0.f;
    for (int rr = 0; rr < 128; ++rr) {
        float a = r[(size_t)(row0 + rr) * FEAT + tid];
        float c = r[(size_t)(row0 + rr) * FEAT + 256 + tid];
        s0 += a; q0 += a * a; s1 += c; q1 += c * c;
    }
    psum[b * FEAT + tid] = s0; psum[b * FEAT + 256 + tid] = s1;
    psq [b * FEAT + tid] = q0; psq [b * FEAT + 256 + tid] = q1;
}

__global__ void bnst2_k(const float* __restrict__ psum, const float* __restrict__ psq,
                        const float* __restrict__ gamma, const float* __restrict__ beta,
                        float* __restrict__ scsh) {
    const int tid = threadIdx.x;
    for (int c = tid; c < FEAT; c += 256) {
        float s = 0.f, q = 0.f;
        for (int b = 0; b < 256; ++b) { s += psum[b * FEAT + c]; q += psq[b * FEAT + c]; }
        float mu = s * (1.0f / (float)NN);
        float var = q * (1.0f / (float)NN) - mu * mu;
        float sc = gamma[c] * rsqrtf(var + 1e-5f);
        scsh[c] = sc;
        scsh[FEAT + c] = beta[c] - mu * sc;
    }
}

// ================= 9. out = x + r*scale + shift (in-place on d_out) =================
__global__ void final_k(const float* __restrict__ x, const float* __restrict__ scsh,
                        float* __restrict__ out) {
    const int total4 = NN * (FEAT / 4);
    for (int idx = blockIdx.x * 256 + threadIdx.x; idx < total4; idx += 2048 * 256) {
        int col4 = idx & (FEAT / 4 - 1);
        float4 rv = *(float4*)&out[(size_t)idx * 4];
        float4 xv = *(const float4*)&x[(size_t)idx * 4];
        float4 sc = *(const float4*)&scsh[col4 * 4];
        float4 sh = *(const float4*)&scsh[FEAT + col4 * 4];
        float4 o = { xv.x + rv.x * sc.x + sh.x, xv.y + rv.y * sc.y + sh.y,
                     xv.z + rv.z * sc.z + sh.z, xv.w + rv.w * sc.w + sh.w };
        *(float4*)&out[(size_t)idx * 4] = o;
    }
}

// =============================== launcher ===============================
extern "C" void kernel_launch(void* const* d_in, const int* in_sizes, int n_in,
                              void* d_out, int out_size, void* d_ws, size_t ws_size,
                              hipStream_t stream) {
    const float* x     = (const float*)d_in[0];
    const int*   ei    = (const int*)d_in[1];
    const float* W1    = (const float*)d_in[5];
    const float* b1    = (const float*)d_in[6];
    const float* W2    = (const float*)d_in[7];
    const float* b2    = (const float*)d_in[8];
    const float* W_in  = (const float*)d_in[9];
    const float* b_in  = (const float*)d_in[10];
    const float* g1W   = (const float*)d_in[11];
    const float* g1b   = (const float*)d_in[12];
    const float* l1W   = (const float*)d_in[13];
    const float* g2W   = (const float*)d_in[14];
    const float* g2b   = (const float*)d_in[15];
    const float* l2W   = (const float*)d_in[16];
    const float* gamma = (const float*)d_in[17];
    const float* beta  = (const float*)d_in[18];
    float* out = (float*)d_out;
    float* ws  = (float*)d_ws;

    float* fv    = ws;                 // [0, 262144)
    float* dvT   = ws + 262144;        // [262144, 524288)  (col-major [8][N])
    float* h0    = ws + 524288;        // [524288, 2621440)
    float* h1    = ws + 2621440;       // [2621440, 4718592)
    unsigned short* W1hi = (unsigned short*)(ws + 262144);  // aliases dvT (written later)
    unsigned short* W1lo = (unsigned short*)(ws + 393216);
    float*        fvpart = ws + 524288;                     // aliases h0 (written later)
    float*        fvT  = ws + 2621440;                      // aliases h1 (written later)
    unsigned int* suvw = (unsigned int*)(ws + 2883584);
    float* s1    = ws + 4718592;
    float* bias1 = ws + 4720640;
    float* s2    = ws + 4722688;
    float* bias2 = ws + 4724736;
    float* psum  = ws + 4741120;
    float* psq   = ws + 4872192;
    float* scsh  = ws + 5003264;

    hipLaunchKernelGGL(w1swz_k,    dim3(64),   dim3(256), 0, stream, W1, W1hi, W1lo);
    hipLaunchKernelGGL(mfma_fv_k,  dim3(1024), dim3(256), 0, stream, x, W1hi, W1lo, b1, W2, fvpart);
    hipLaunchKernelGGL(fvred_k,    dim3(128),  dim3(256), 0, stream, fvpart, b2, fv, fvT);
    hipLaunchKernelGGL(uf_sort_k,  dim3(256),  dim3(512), 0, stream, fvT, ei, suvw);
    hipLaunchKernelGGL(uf_merge_k, dim3(256),  dim3(256), 0, stream, fvT, suvw, dvT);
    hipLaunchKernelGGL(feat_k,     dim3(128),  dim3(256), 0, stream, fv, dvT, W_in, b_in, h0);
    hipLaunchKernelGGL(reduce64_k, dim3(32),   dim3(256), 0, stream, h0, s1);
    hipLaunchKernelGGL(lam_k,      dim3(32),   dim3(256), 0, stream, s1, l1W, g1b, bias1, 64);
    hipLaunchKernelGGL(ds1_k,      dim3(128),  dim3(256), 0, stream, h0, g1W, bias1, h1);
    hipLaunchKernelGGL(reduce64_k, dim3(32),   dim3(256), 0, stream, h1, s2);
    hipLaunchKernelGGL(lam_k,      dim3(32),   dim3(256), 0, stream, s2, l2W, g2b, bias2, 512);
    hipLaunchKernelGGL(ds2_k,      dim3(1024), dim3(256), 0, stream, h1, g2W, bias2, out);
    hipLaunchKernelGGL(bnst1_k,    dim3(256),  dim3(256), 0, stream, out, psum, psq);
    hipLaunchKernelGGL(bnst2_k,    dim3(1),    dim3(256), 0, stream, psum, psq, gamma, beta, scsh);
    hipLaunchKernelGGL(final_k,    dim3(2048), dim3(256), 0, stream, x, scsh, out);
}

// Round 16
// 650.537 us; speedup vs baseline: 1.2404x; 1.0003x over previous
//
#include <hip/hip_runtime.h>
#include <stdint.h>

// ---------------- problem constants (fixed by setup_inputs) ----------------
static constexpr int NN    = 32768;   // nodes
static constexpr int NPG   = 1024;    // nodes per graph
static constexpr int EPG   = 2048;    // edges per graph
static constexpr int NGR   = 32;      // graphs
static constexpr int NF    = 8;       // filtrations
static constexpr int FEAT  = 512;
static constexpr int ODIM  = 64;
static constexpr int ETOT  = NGR * EPG;

typedef short bf16x8 __attribute__((ext_vector_type(8)));
typedef float f32x4  __attribute__((ext_vector_type(4)));

// order-preserving float -> uint key
__device__ __forceinline__ unsigned int fsort(float f) {
    unsigned int u = __float_as_uint(f);
    return (u & 0x80000000u) ? ~u : (u | 0x80000000u);
}

// split two f32 into packed bf16-hi pair and bf16-lo pair (truncation split).
__device__ __forceinline__ void split2(float a, float b, unsigned& hi, unsigned& lo) {
    unsigned ua = __float_as_uint(a), ub = __float_as_uint(b);
    hi = (ua >> 16) | (ub & 0xffff0000u);
    float ra = a - __uint_as_float(ua & 0xffff0000u);
    float rb = b - __uint_as_float(ub & 0xffff0000u);
    lo = (__float_as_uint(ra) >> 16) | (__float_as_uint(rb) & 0xffff0000u);
}

// ========== 0. W1 -> transposed, split (hi/lo bf16), tile-swizzled ==========
__global__ __launch_bounds__(256) void w1swz_k(
        const float* __restrict__ W1,
        unsigned short* __restrict__ Whi, unsigned short* __restrict__ Wlo) {
    __shared__ float T[64][65];
    const int tid = threadIdx.x;
    const int kb = blockIdx.x >> 3, cb = blockIdx.x & 7;
    const int r16 = tid >> 4, c4 = tid & 15;
#pragma unroll
    for (int p = 0; p < 4; ++p) {
        int kl = r16 + p * 16;
        *(float4*)&T[kl][c4 * 4] = *(const float4*)&W1[(size_t)(kb * 64 + kl) * FEAT + cb * 64 + c4 * 4];
    }
    __syncthreads();
    const int col_l = tid >> 2;
    const int col = cb * 64 + col_l;
    const int sw = (col + (col >> 2)) & 3;
#pragma unroll
    for (int q = 0; q < 2; ++q) {
        int ch = (tid & 3) + q * 4;
        int ktl = ch >> 2, slot = ch & 3;
        int koff = slot ^ sw;
        unsigned hi[4], lo[4];
#pragma unroll
        for (int pj = 0; pj < 4; ++pj) {
            float a = T[ktl * 32 + koff * 8 + pj * 2 + 0][col_l];
            float b = T[ktl * 32 + koff * 8 + pj * 2 + 1][col_l];
            split2(a, b, hi[pj], lo[pj]);
        }
        size_t o = (size_t)col * 512 + (size_t)kb * 64 + ktl * 32 + slot * 8;
        *(uint4*)&Whi[o] = make_uint4(hi[0], hi[1], hi[2], hi[3]);
        *(uint4*)&Wlo[o] = make_uint4(lo[0], lo[1], lo[2], lo[3]);
    }
}

// ========== 1a. split-bf16 MFMA GEMM fused with relu+b1 then @W2 ==========
__global__ __launch_bounds__(256, 2) void mfma_fv_k(
        const float* __restrict__ x, const unsigned short* __restrict__ Whi,
        const unsigned short* __restrict__ Wlo, const float* __restrict__ b1,
        const float* __restrict__ W2, float* __restrict__ fvpart) {
    __shared__ unsigned short AsHi[4096], AsLo[4096], BsHi[4096], BsLo[4096];
    __shared__ float W2s[128][8];
    __shared__ float b1s[128];

    const int tid = threadIdx.x;
    const int lane = tid & 63, wid = tid >> 6;
    const int wr = wid >> 1, wc = wid & 1;
    const int b = blockIdx.x;
    const int rb = (b & 7) * 32 + (b >> 5);
    const int cb = (b >> 3) & 3;
    const int rowBase = rb * 128, colBase = cb * 128;

    for (int i = tid; i < 1024; i += 256)
        W2s[i >> 3][i & 7] = W2[(size_t)(colBase + (i >> 3)) * NF + (i & 7)];
    if (tid < 128) b1s[tid] = b1[colBase + tid];

    const int arow = tid >> 1, ah2 = tid & 1;
    const int aswz = (arow + (arow >> 2)) & 3;
    const float* xp = x + (size_t)(rowBase + arow) * FEAT + ah2 * 16;
    const int bcol = tid >> 1;
    const size_t bsrc = (size_t)(colBase + bcol) * 512 + (size_t)(tid & 1) * 16;
    const int bdst = bcol * 32 + (tid & 1) * 16;

    f32x4 acc[4][4];
#pragma unroll
    for (int m = 0; m < 4; ++m)
#pragma unroll
        for (int n = 0; n < 4; ++n) acc[m][n] = (f32x4){0.f, 0.f, 0.f, 0.f};

    float4 av[4];
    uint4 bhv[2], blv[2];
    av[0] = ((const float4*)xp)[0]; av[1] = ((const float4*)xp)[1];
    av[2] = ((const float4*)xp)[2]; av[3] = ((const float4*)xp)[3];
    bhv[0] = *(const uint4*)(Whi + bsrc); bhv[1] = *(const uint4*)(Whi + bsrc + 8);
    blv[0] = *(const uint4*)(Wlo + bsrc); blv[1] = *(const uint4*)(Wlo + bsrc + 8);

    for (int tk = 0; tk < 16; ++tk) {
        __syncthreads();
#pragma unroll
        for (int cj = 0; cj < 2; ++cj) {
            int koff = ah2 * 2 + cj;
            int slot = koff ^ aswz;
            unsigned h0, h1, h2, h3, l0, l1, l2, l3;
            split2(av[cj * 2 + 0].x, av[cj * 2 + 0].y, h0, l0);
            split2(av[cj * 2 + 0].z, av[cj * 2 + 0].w, h1, l1);
            split2(av[cj * 2 + 1].x, av[cj * 2 + 1].y, h2, l2);
            split2(av[cj * 2 + 1].z, av[cj * 2 + 1].w, h3, l3);
            int o = arow * 32 + slot * 8;
            *(uint4*)&AsHi[o] = make_uint4(h0, h1, h2, h3);
            *(uint4*)&AsLo[o] = make_uint4(l0, l1, l2, l3);
        }
        *(uint4*)&BsHi[bdst] = bhv[0]; *(uint4*)&BsHi[bdst + 8] = bhv[1];
        *(uint4*)&BsLo[bdst] = blv[0]; *(uint4*)&BsLo[bdst + 8] = blv[1];
        if (tk < 15) {
            const float* xq = xp + (tk + 1) * 32;
            av[0] = ((const float4*)xq)[0]; av[1] = ((const float4*)xq)[1];
            av[2] = ((const float4*)xq)[2]; av[3] = ((const float4*)xq)[3];
            const unsigned short* bh = Whi + bsrc + (size_t)(tk + 1) * 32;
            const unsigned short* bl = Wlo + bsrc + (size_t)(tk + 1) * 32;
            bhv[0] = *(const uint4*)bh; bhv[1] = *(const uint4*)(bh + 8);
            blv[0] = *(const uint4*)bl; blv[1] = *(const uint4*)(bl + 8);
        }
        __syncthreads();
        bf16x8 fa[4], fb[4], f2[4];
#pragma unroll
        for (int m = 0; m < 4; ++m) {
            int r = wr * 64 + m * 16 + (lane & 15);
            int slot = (lane >> 4) ^ ((r + (r >> 2)) & 3);
            fa[m] = *(const bf16x8*)&AsHi[r * 32 + slot * 8];
        }
#pragma unroll
        for (int n = 0; n < 4; ++n) {
            int c = wc * 64 + n * 16 + (lane & 15);
            int slot = (lane >> 4) ^ ((c + (c >> 2)) & 3);
            fb[n] = *(const bf16x8*)&BsHi[c * 32 + slot * 8];
        }
#pragma unroll
        for (int m = 0; m < 4; ++m)
#pragma unroll
            for (int n = 0; n < 4; ++n)
                acc[m][n] = __builtin_amdgcn_mfma_f32_16x16x32_bf16(fa[m], fb[n], acc[m][n], 0, 0, 0);
#pragma unroll
        for (int n = 0; n < 4; ++n) {
            int c = wc * 64 + n * 16 + (lane & 15);
            int slot = (lane >> 4) ^ ((c + (c >> 2)) & 3);
            f2[n] = *(const bf16x8*)&BsLo[c * 32 + slot * 8];
        }
#pragma unroll
        for (int m = 0; m < 4; ++m)
#pragma unroll
            for (int n = 0; n < 4; ++n)
                acc[m][n] = __builtin_amdgcn_mfma_f32_16x16x32_bf16(fa[m], f2[n], acc[m][n], 0, 0, 0);
#pragma unroll
        for (int m = 0; m < 4; ++m) {
            int r = wr * 64 + m * 16 + (lane & 15);
            int slot = (lane >> 4) ^ ((r + (r >> 2)) & 3);
            f2[m] = *(const bf16x8*)&AsLo[r * 32 + slot * 8];
        }
#pragma unroll
        for (int m = 0; m < 4; ++m)
#pragma unroll
            for (int n = 0; n < 4; ++n)
                acc[m][n] = __builtin_amdgcn_mfma_f32_16x16x32_bf16(f2[m], fb[n], acc[m][n], 0, 0, 0);
    }

    const int p = cb * 2 + wc;
#pragma unroll
    for (int m = 0; m < 4; ++m) {
        float pf[4][8];
#pragma unroll
        for (int r = 0; r < 4; ++r)
#pragma unroll
            for (int j = 0; j < 8; ++j) pf[r][j] = 0.f;
#pragma unroll
        for (int n = 0; n < 4; ++n) {
            int c = wc * 64 + n * 16 + (lane & 15);
            float bc = b1s[c];
            float4 wA = *(const float4*)&W2s[c][0];
            float4 wB = *(const float4*)&W2s[c][4];
#pragma unroll
            for (int r = 0; r < 4; ++r) {
                float h = fmaxf(acc[m][n][r] + bc, 0.f);
                pf[r][0] += h * wA.x; pf[r][1] += h * wA.y; pf[r][2] += h * wA.z; pf[r][3] += h * wA.w;
                pf[r][4] += h * wB.x; pf[r][5] += h * wB.y; pf[r][6] += h * wB.z; pf[r][7] += h * wB.w;
            }
        }
#pragma unroll
        for (int mask = 1; mask <= 8; mask <<= 1)
#pragma unroll
            for (int r = 0; r < 4; ++r)
#pragma unroll
                for (int j = 0; j < 8; ++j) pf[r][j] += __shfl_xor(pf[r][j], mask);
        if ((lane & 15) == 0) {
            int rowb = rowBase + wr * 64 + m * 16 + (lane >> 4) * 4;
#pragma unroll
            for (int r = 0; r < 4; ++r) {
                *(float4*)&fvpart[(((size_t)p << 15) + rowb + r) * NF + 0] =
                    make_float4(pf[r][0], pf[r][1], pf[r][2], pf[r][3]);
                *(float4*)&fvpart[(((size_t)p << 15) + rowb + r) * NF + 4] =
                    make_float4(pf[r][4], pf[r][5], pf[r][6], pf[r][7]);
            }
        }
    }
}

// ========== 1b. fv = sum of 8 panels + b2; writes fv [N][8] and fvT [8][N] ==========
__global__ __launch_bounds__(256) void fvred_k(
        const float* __restrict__ fvpart, const float* __restrict__ b2,
        float* __restrict__ fv, float* __restrict__ fvT) {
    const int row = blockIdx.x * 256 + threadIdx.x;
    float s[8];
    *(float4*)&s[0] = *(const float4*)&b2[0];
    *(float4*)&s[4] = *(const float4*)&b2[4];
#pragma unroll
    for (int p = 0; p < 8; ++p) {
        float4 lo = *(const float4*)&fvpart[(((size_t)p << 15) + row) * NF + 0];
        float4 hi = *(const float4*)&fvpart[(((size_t)p << 15) + row) * NF + 4];
        s[0] += lo.x; s[1] += lo.y; s[2] += lo.z; s[3] += lo.w;
        s[4] += hi.x; s[5] += hi.y; s[6] += hi.z; s[7] += hi.w;
    }
    *(float4*)&fv[(size_t)row * NF + 0] = *(float4*)&s[0];
    *(float4*)&fv[(size_t)row * NF + 4] = *(float4*)&s[4];
#pragma unroll
    for (int j = 0; j < 8; ++j) fvT[(size_t)j * NN + row] = s[j];
}

// ============ 2a. per-(graph,filtration) edge key build + bitonic sort ============
__global__ __launch_bounds__(512) void uf_sort_k(
        const float* __restrict__ fvT, const int* __restrict__ ei,
        unsigned int* __restrict__ suvw) {
    __shared__ float fvl[NPG];
    __shared__ unsigned long long keys[EPG];
    __shared__ unsigned int uvw[EPG];
    const int tid = threadIdx.x;
    const int g = blockIdx.x >> 3, k = blockIdx.x & 7;

    for (int i = tid; i < NPG; i += 512) fvl[i] = fvT[(size_t)k * NN + (g << 10) + i];
    __syncthreads();
    for (int e = tid; e < EPG; e += 512) {
        int eg = g * EPG + e;
        int u = ei[eg] & (NPG - 1);
        int v = ei[ETOT + eg] & (NPG - 1);
        unsigned int fku = fsort(fvl[u]);
        unsigned int fkv = fsort(fvl[v]);
        unsigned int wfl = (fku > fkv || (fku == fkv && u >= v)) ? 1u : 0u;
        unsigned int fe = fku > fkv ? fku : fkv;
        uvw[e] = (unsigned)u | ((unsigned)v << 10) | (wfl << 20);
        keys[e] = ((unsigned long long)fe << 32) | (unsigned)e;
    }
    for (int size = 2; size <= EPG; size <<= 1) {
        for (int stride = size >> 1; stride > 0; stride >>= 1) {
            __syncthreads();
            for (int i = tid; i < EPG; i += 512) {
                int j = i ^ stride;
                if (j > i) {
                    unsigned long long a = keys[i], b = keys[j];
                    bool asc = (i & size) == 0;
                    if (asc ? (a > b) : (a < b)) { keys[i] = b; keys[j] = a; }
                }
            }
        }
    }
    __syncthreads();
    for (int i = tid; i < EPG; i += 512)
        suvw[(size_t)blockIdx.x * EPG + i] = uvw[(unsigned)(keys[i] & 0xffffffffULL)];
}

// ============ 2b. EXACT sequential union-find: 2 batched passes + serial tail ============
// grid 256 blocks, 256 threads (staging + output); wave 0 executes the merge.
// node word: [fkey:32 | birth_idx:16 | parent:16]. UNION-BY-ELDER: young root
// links under elder root; elder root's record is invariant.
// Per 64-edge window:
//   (A) up to 2 BATCHED passes using the round-13 HW-VALIDATED rule verbatim:
//       atomicMin-claim young root; win iff claim-winner AND lane < first
//       blocked alive lane (prefix cut); winners commit in parallel (distinct
//       youngs, disjoint writes); claims reset; survivors fully re-chase and
//       re-read records. Drains the ~80% contention-free commits fast.
//   (B) SERIAL TAIL using the round-14 HW-VALIDATED ballot loop verbatim:
//       lowest alive lane commits; 3-shfl broadcast {rY|rE, wE}; lanes patch
//       roots/records in registers; LDS writes deferred to window end
//       (disjoint targets). Committed lane self-retires via its own patch
//       (ru==rv), so no explicit lane>li term is needed.
__global__ __launch_bounds__(256) void uf_merge_k(
        const float* __restrict__ fvT, const unsigned int* __restrict__ suvw,
        float* __restrict__ dvT) {
    __shared__ float fvl[NPG];
    __shared__ unsigned long long node[NPG];
    __shared__ unsigned short deathl[NPG];
    __shared__ unsigned int se[EPG];
    __shared__ unsigned int claim[NPG];

    const int tid = threadIdx.x;
    const int g = blockIdx.x >> 3, k = blockIdx.x & 7;

    for (int i = tid; i < NPG; i += 256) {
        float val = fvT[(size_t)k * NN + (g << 10) + i];
        fvl[i] = val;
        node[i] = ((unsigned long long)fsort(val) << 32) | ((unsigned long long)(unsigned)i << 16) | (unsigned)i;
        deathl[i] = (unsigned short)i;
        claim[i] = ~0u;
    }
    for (int i = tid; i < EPG / 4; i += 256)
        ((uint4*)se)[i] = ((const uint4*)(suvw + (size_t)blockIdx.x * EPG))[i];
    __syncthreads();

    if (tid < 64) {
        const int lane = tid;
        volatile unsigned int* vn32 = (volatile unsigned int*)node;
        volatile unsigned long long* vn64 = (volatile unsigned long long*)node;
        volatile unsigned int* vcl = (volatile unsigned int*)claim;
        for (int w = 0; w < EPG / 64; ++w) {
            unsigned int pk = se[w * 64 + lane];
            int u = (int)(pk & 1023u), v = (int)((pk >> 10) & 1023u);
            int wd = ((pk >> 20) & 1u) ? u : v;       // death vertex (static)
            // initial chase with path-halving (low-dword writes keep birth bits)
            int ru = u;
            {
                unsigned int lw = vn32[ru * 2];
                int p = (int)(lw & 0xffffu);
                while (p != ru) {
                    unsigned int lw2 = vn32[p * 2];
                    int gp = (int)(lw2 & 0xffffu);
                    if (gp != p) vn32[ru * 2] = (lw & 0xffff0000u) | (unsigned)gp;
                    ru = p; lw = lw2; p = gp;
                }
            }
            int rv = v;
            {
                unsigned int lw = vn32[rv * 2];
                int p = (int)(lw & 0xffffu);
                while (p != rv) {
                    unsigned int lw2 = vn32[p * 2];
                    int gp = (int)(lw2 & 0xffffu);
                    if (gp != p) vn32[rv * 2] = (lw & 0xffff0000u) | (unsigned)gp;
                    rv = p; lw = lw2; p = gp;
                }
            }
            unsigned long long wa = vn64[ru];
            unsigned long long wb = vn64[rv];
            bool alive = (ru != rv);

            // ---- (A) two batched passes, round-13 rule verbatim ----
            for (int bp = 0; bp < 2; ++bp) {
                if (__ballot(alive) == 0) break;
                bool wasAlive = alive;
                int ry = 0, re = 0;
                unsigned long long wy = 0;
                if (alive) {
                    bool uY = (wa >> 16) > (wb >> 16);   // young = larger (fkey,birth)
                    ry = uY ? ru : rv; re = uY ? rv : ru;
                    wy = uY ? wa : wb;
                    atomicMin(&claim[ry], (unsigned)lane);
                }
                bool win0 = alive && (vcl[ry] == (unsigned)lane);
                unsigned long long blockedM = __ballot(alive && !win0);
                int fb = blockedM ? (int)__builtin_ctzll(blockedM) : 64;
                bool win = win0 && (lane < fb);
                if (win) {
                    deathl[(int)((wy >> 16) & 0xffffu)] = (unsigned short)wd;
                    vn64[ry] = (wy & ~0xffffULL) | (unsigned)re;
                    alive = false;
                }
                if (wasAlive) vcl[ry] = ~0u;             // writers reset claims
                if (alive) {                              // survivors: full re-chase
                    int r = ru;
                    unsigned int lw = vn32[r * 2];
                    int p = (int)(lw & 0xffffu);
                    while (p != r) {
                        unsigned int lw2 = vn32[p * 2];
                        int gp = (int)(lw2 & 0xffffu);
                        if (gp != p) vn32[r * 2] = (lw & 0xffff0000u) | (unsigned)gp;
                        r = p; lw = lw2; p = gp;
                    }
                    ru = r;
                    r = rv;
                    lw = vn32[r * 2];
                    p = (int)(lw & 0xffffu);
                    while (p != r) {
                        unsigned int lw2 = vn32[p * 2];
                        int gp = (int)(lw2 & 0xffffu);
                        if (gp != p) vn32[r * 2] = (lw & 0xffff0000u) | (unsigned)gp;
                        r = p; lw = lw2; p = gp;
                    }
                    rv = r;
                    wa = vn64[ru]; wb = vn64[rv];
                    alive = (ru != rv);
                }
            }

            // ---- (B) serial tail, round-14 loop verbatim ----
            bool committed = false;
            int cY = 0, cE = 0;
            unsigned long long cW = 0;
            unsigned long long mask = __ballot(alive);
            while (mask) {
                int li = (int)__builtin_ctzll(mask);   // lowest alive lane = sorted order
                bool uE = (wa >> 16) <= (wb >> 16);
                int rE_l = uE ? ru : rv;
                int rY_l = uE ? rv : ru;
                unsigned long long wE_l = uE ? wa : wb;
                unsigned long long wY_l = uE ? wb : wa;
                unsigned pk2 = (unsigned)rY_l | ((unsigned)rE_l << 10);
                unsigned bpk = __shfl(pk2, li);
                unsigned belo = __shfl((unsigned)wE_l, li);
                unsigned behi = __shfl((unsigned)(wE_l >> 32), li);
                unsigned long long bwE = ((unsigned long long)behi << 32) | belo;
                int brY = (int)(bpk & 1023u), brE = (int)((bpk >> 10) & 1023u);
                if (lane == li) { committed = true; cY = rY_l; cE = rE_l; cW = wY_l; }
                if (ru == brY) { ru = brE; wa = bwE; }
                if (rv == brY) { rv = brE; wb = bwE; }
                alive = alive && (ru != rv);           // committed lane self-retires
                mask = __ballot(alive);
            }
            // flush: disjoint young-root links + death records
            if (committed) {
                deathl[(int)((cW >> 16) & 0xffffu)] = (unsigned short)wd;
                vn64[cY] = (cW & ~0xffffULL) | (unsigned)cE;
            }
            __builtin_amdgcn_wave_barrier();
        }
    }
    __syncthreads();
    for (int i = tid; i < NPG; i += 256)
        dvT[(size_t)k * NN + (g << 10) + i] = fvl[deathl[i]];
}

// ================= 3. h0 = relu(x0 @ W_in + b_in), x0 = interleave(fv,dvT) =================
__global__ __launch_bounds__(256, 2) void feat_k(
        const float* __restrict__ fv, const float* __restrict__ dvT,
        const float* __restrict__ W_in, const float* __restrict__ b_in,
        float* __restrict__ h0) {
    __shared__ float Ws[16][64];
    __shared__ float bs[64];
    const int tid = threadIdx.x;
    for (int i = tid; i < 1024; i += 256) Ws[i >> 6][i & 63] = W_in[i];
    if (tid < 64) bs[tid] = b_in[tid];
    __syncthreads();
    const int n = blockIdx.x * 256 + tid;
    float4 f0 = *(const float4*)&fv[(size_t)n * NF + 0];
    float4 f1 = *(const float4*)&fv[(size_t)n * NF + 4];
    float dd[8];
#pragma unroll
    for (int j = 0; j < 8; ++j) dd[j] = dvT[(size_t)j * NN + n];
    float x0[16] = { f0.x, dd[0], f0.y, dd[1], f0.z, dd[2], f0.w, dd[3],
                     f1.x, dd[4], f1.y, dd[5], f1.z, dd[6], f1.w, dd[7] };
    float out[64];
#pragma unroll
    for (int j = 0; j < 64; ++j) out[j] = bs[j];
#pragma unroll
    for (int i = 0; i < 16; ++i) {
        float a = x0[i];
#pragma unroll
        for (int j4 = 0; j4 < 16; ++j4) {
            float4 w = *(const float4*)&Ws[i][j4 * 4];
            out[j4 * 4 + 0] += a * w.x; out[j4 * 4 + 1] += a * w.y;
            out[j4 * 4 + 2] += a * w.z; out[j4 * 4 + 3] += a * w.w;
        }
    }
#pragma unroll
    for (int j4 = 0; j4 < 16; ++j4) {
        float4 o = { fmaxf(out[j4 * 4 + 0], 0.f), fmaxf(out[j4 * 4 + 1], 0.f),
                     fmaxf(out[j4 * 4 + 2], 0.f), fmaxf(out[j4 * 4 + 3], 0.f) };
        *(float4*)&h0[(size_t)n * 64 + j4 * 4] = o;
    }
}

// ===== 4. fused per-graph column sums + bias[g][j] = Gb[j] - (s[g]/1024)@LW =====
__global__ void redlam_k(const float* __restrict__ h, const float* __restrict__ LW,
                         const float* __restrict__ Gb, float* __restrict__ bias, int Fout) {
    __shared__ float part[4][64];
    __shared__ float sg[64];
    const int tid = threadIdx.x, g = blockIdx.x;
    const int c = tid & 63, rg = tid >> 6;
    float acc = 0.f;
    for (int r = rg; r < NPG; r += 4) acc += h[(size_t)(g * NPG + r) * 64 + c];
    part[rg][c] = acc;
    __syncthreads();
    if (tid < 64) sg[tid] = (part[0][tid] + part[1][tid] + part[2][tid] + part[3][tid]) * (1.0f / 1024.0f);
    __syncthreads();
    for (int j = tid; j < Fout; j += 256) {
        float a = 0.f;
        for (int i = 0; i < 64; ++i) a += sg[i] * LW[i * Fout + j];
        bias[g * Fout + j] = Gb[j] - a;
    }
}

// ================= 6. h1 = relu(h0 @ g1W + bias1[g]) =================
__global__ __launch_bounds__(256, 2) void ds1_k(
        const float* __restrict__ h0, const float* __restrict__ g1W,
        const float* __restrict__ bias1, float* __restrict__ h1) {
    __shared__ float Ws[64][64];
    const int tid = threadIdx.x;
    for (int i = tid; i < 4096; i += 256) Ws[i >> 6][i & 63] = g1W[i];
    __syncthreads();
    const int n = blockIdx.x * 256 + tid;
    const int g = n >> 10;
    float in[64];
#pragma unroll
    for (int i4 = 0; i4 < 16; ++i4) {
        float4 t = *(const float4*)&h0[(size_t)n * 64 + i4 * 4];
        in[i4 * 4 + 0] = t.x; in[i4 * 4 + 1] = t.y; in[i4 * 4 + 2] = t.z; in[i4 * 4 + 3] = t.w;
    }
    float out[64];
#pragma unroll
    for (int j4 = 0; j4 < 16; ++j4) {
        float4 b = *(const float4*)&bias1[g * 64 + j4 * 4];
        out[j4 * 4 + 0] = b.x; out[j4 * 4 + 1] = b.y; out[j4 * 4 + 2] = b.z; out[j4 * 4 + 3] = b.w;
    }
#pragma unroll 8
    for (int i = 0; i < 64; ++i) {
        float a = in[i];
#pragma unroll
        for (int j4 = 0; j4 < 16; ++j4) {
            float4 w = *(const float4*)&Ws[i][j4 * 4];
            out[j4 * 4 + 0] += a * w.x; out[j4 * 4 + 1] += a * w.y;
            out[j4 * 4 + 2] += a * w.z; out[j4 * 4 + 3] += a * w.w;
        }
    }
#pragma unroll
    for (int j4 = 0; j4 < 16; ++j4) {
        float4 o = { fmaxf(out[j4 * 4 + 0], 0.f), fmaxf(out[j4 * 4 + 1], 0.f),
                     fmaxf(out[j4 * 4 + 2], 0.f), fmaxf(out[j4 * 4 + 3], 0.f) };
        *(float4*)&h1[(size_t)n * 64 + j4 * 4] = o;
    }
}

// ================= 7. r = relu(h1 @ g2W + bias2[g]) -> d_out =================
__global__ __launch_bounds__(256, 2) void ds2_k(
        const float* __restrict__ h1, const float* __restrict__ g2W,
        const float* __restrict__ bias2, float* __restrict__ rout) {
    __shared__ float Ht[32][68];
    __shared__ float Wt[64][68];
    const int tid = threadIdx.x;
    const int rowBase = blockIdx.x * 32;
    const int g = rowBase >> 10;
#pragma unroll
    for (int p = 0; p < 2; ++p) {
        int fid = tid + p * 256;
        int r = fid >> 4, c4 = fid & 15;
        *(float4*)&Ht[r][c4 * 4] = *(const float4*)&h1[(size_t)(rowBase + r) * 64 + c4 * 4];
    }
    const int cg = tid & 15, rg = tid >> 4;
    for (int nc = 0; nc < 8; ++nc) {
        __syncthreads();
#pragma unroll
        for (int p = 0; p < 4; ++p) {
            int fid = tid + p * 256;
            int kk = fid >> 4, c4 = fid & 15;
            *(float4*)&Wt[kk][c4 * 4] = *(const float4*)&g2W[(size_t)kk * FEAT + nc * 64 + c4 * 4];
        }
        __syncthreads();
        float a0[4] = {0.f, 0.f, 0.f, 0.f}, a1[4] = {0.f, 0.f, 0.f, 0.f};
#pragma unroll 8
        for (int kk = 0; kk < 64; ++kk) {
            float h0v = Ht[rg * 2][kk], h1v = Ht[rg * 2 + 1][kk];
            float4 w = *(const float4*)&Wt[kk][cg * 4];
            a0[0] += h0v * w.x; a0[1] += h0v * w.y; a0[2] += h0v * w.z; a0[3] += h0v * w.w;
            a1[0] += h1v * w.x; a1[1] += h1v * w.y; a1[2] += h1v * w.z; a1[3] += h1v * w.w;
        }
        float4 bv = *(const float4*)&bias2[g * FEAT + nc * 64 + cg * 4];
        int row0 = rowBase + rg * 2;
        float4 o0 = { fmaxf(a0[0] + bv.x, 0.f), fmaxf(a0[1] + bv.y, 0.f),
                      fmaxf(a0[2] + bv.z, 0.f), fmaxf(a0[3] + bv.w, 0.f) };
        float4 o1 = { fmaxf(a1[0] + bv.x, 0.f), fmaxf(a1[1] + bv.y, 0.f),
                      fmaxf(a1[2] + bv.z, 0.f), fmaxf(a1[3] + bv.w, 0.f) };
        *(float4*)&rout[(size_t)row0 * FEAT + nc * 64 + cg * 4] = o0;
        *(float4*)&rout[(size_t)(row0 + 1) * FEAT + nc * 64 + cg * 4] = o1;
    }
}

// ================= 8. BN stats =================
__global__ void bnst1_k(const float* __restrict__ r, float* __restrict__ psum, float* __restrict__ psq) {
    const int tid = threadIdx.x, b = blockIdx.x;
    const int row0 = b * 128;
    float s0 = 0.f, q0 = 0.f, s1 = 0.f, q1 = 0.f;
    for (int rr = 0; rr < 128; ++rr) {
        float a = r[(size_t)(row0 + rr) * FEAT + tid];
        float c = r[(size_t)(row0 + rr) * FEAT + 256 + tid];
        s0 += a; q0 += a * a; s1 += c; q1 += c * c;
    }
    psum[b * FEAT + tid] = s0; psum[b * FEAT + 256 + tid] = s1;
    psq [b * FEAT + tid] = q0; psq [b * FEAT + 256 + tid] = q1;
}

__global__ void bnst2_k(const float* __restrict__ psum, const float* __restrict__ psq,
                        const float* __restrict__ gamma, const float* __restrict__ beta,
                        float* __restrict__ scsh) {
    const int tid = threadIdx.x;
    for (int c = tid; c < FEAT; c += 256) {
        float s = 0.f, q = 0.f;
        for (int b = 0; b < 256; ++b) { s += psum[b * FEAT + c]; q += psq[b * FEAT + c]; }
        float mu = s * (1.0f / (float)NN);
        float var = q * (1.0f / (float)NN) - mu * mu;
        float sc = gamma[c] * rsqrtf(var + 1e-5f);
        scsh[c] = sc;
        scsh[FEAT + c] = beta[c] - mu * sc;
    }
}

// ================= 9. out = x + r*scale + shift (in-place on d_out) =================
__global__ void final_k(const float* __restrict__ x, const float* __restrict__ scsh,
                        float* __restrict__ out) {
    const int total4 = NN * (FEAT / 4);
    for (int idx = blockIdx.x * 256 + threadIdx.x; idx < total4; idx += 2048 * 256) {
        int col4 = idx & (FEAT / 4 - 1);
        float4 rv = *(float4*)&out[(size_t)idx * 4];
        float4 xv = *(const float4*)&x[(size_t)idx * 4];
        float4 sc = *(const float4*)&scsh[col4 * 4];
        float4 sh = *(const float4*)&scsh[FEAT + col4 * 4];
        float4 o = { xv.x + rv.x * sc.x + sh.x, xv.y + rv.y * sc.y + sh.y,
                     xv.z + rv.z * sc.z + sh.z, xv.w + rv.w * sc.w + sh.w };
        *(float4*)&out[(size_t)idx * 4] = o;
    }
}

// =============================== launcher ===============================
extern "C" void kernel_launch(void* const* d_in, const int* in_sizes, int n_in,
                              void* d_out, int out_size, void* d_ws, size_t ws_size,
                              hipStream_t stream) {
    const float* x     = (const float*)d_in[0];
    const int*   ei    = (const int*)d_in[1];
    const float* W1    = (const float*)d_in[5];
    const float* b1    = (const float*)d_in[6];
    const float* W2    = (const float*)d_in[7];
    const float* b2    = (const float*)d_in[8];
    const float* W_in  = (const float*)d_in[9];
    const float* b_in  = (const float*)d_in[10];
    const float* g1W   = (const float*)d_in[11];
    const float* g1b   = (const float*)d_in[12];
    const float* l1W   = (const float*)d_in[13];
    const float* g2W   = (const float*)d_in[14];
    const float* g2b   = (const float*)d_in[15];
    const float* l2W   = (const float*)d_in[16];
    const float* gamma = (const float*)d_in[17];
    const float* beta  = (const float*)d_in[18];
    float* out = (float*)d_out;
    float* ws  = (float*)d_ws;

    float* fv    = ws;                 // [0, 262144)
    float* dvT   = ws + 262144;        // [262144, 524288)  (col-major [8][N])
    float* h0    = ws + 524288;        // [524288, 2621440)
    float* h1    = ws + 2621440;       // [2621440, 4718592)
    unsigned short* W1hi = (unsigned short*)(ws + 262144);  // aliases dvT (written later)
    unsigned short* W1lo = (unsigned short*)(ws + 393216);
    float*        fvpart = ws + 524288;                     // aliases h0 (written later)
    float*        fvT  = ws + 2621440;                      // aliases h1 (written later)
    unsigned int* suvw = (unsigned int*)(ws + 2883584);
    float* bias1 = ws + 4720640;
    float* bias2 = ws + 4724736;
    float* psum  = ws + 4741120;
    float* psq   = ws + 4872192;
    float* scsh  = ws + 5003264;

    hipLaunchKernelGGL(w1swz_k,    dim3(64),   dim3(256), 0, stream, W1, W1hi, W1lo);
    hipLaunchKernelGGL(mfma_fv_k,  dim3(1024), dim3(256), 0, stream, x, W1hi, W1lo, b1, W2, fvpart);
    hipLaunchKernelGGL(fvred_k,    dim3(128),  dim3(256), 0, stream, fvpart, b2, fv, fvT);
    hipLaunchKernelGGL(uf_sort_k,  dim3(256),  dim3(512), 0, stream, fvT, ei, suvw);
    hipLaunchKernelGGL(uf_merge_k, dim3(256),  dim3(256), 0, stream, fvT, suvw, dvT);
    hipLaunchKernelGGL(feat_k,     dim3(128),  dim3(256), 0, stream, fv, dvT, W_in, b_in, h0);
    hipLaunchKernelGGL(redlam_k,   dim3(32),   dim3(256), 0, stream, h0, l1W, g1b, bias1, 64);
    hipLaunchKernelGGL(ds1_k,      dim3(128),  dim3(256), 0, stream, h0, g1W, bias1, h1);
    hipLaunchKernelGGL(redlam_k,   dim3(32),   dim3(256), 0, stream, h1, l2W, g2b, bias2, 512);
    hipLaunchKernelGGL(ds2_k,      dim3(1024), dim3(256), 0, stream, h1, g2W, bias2, out);
    hipLaunchKernelGGL(bnst1_k,    dim3(256),  dim3(256), 0, stream, out, psum, psq);
    hipLaunchKernelGGL(bnst2_k,    dim3(1),    dim3(256), 0, stream, psum, psq, gamma, beta, scsh);
    hipLaunchKernelGGL(final_k,    dim3(2048), dim3(256), 0, stream, x, scsh, out);
}

// Round 17
// 623.237 us; speedup vs baseline: 1.2947x; 1.0438x over previous
//
#include <hip/hip_runtime.h>
#include <stdint.h>

// ---------------- problem constants (fixed by setup_inputs) ----------------
static constexpr int NN    = 32768;   // nodes
static constexpr int NPG   = 1024;    // nodes per graph
static constexpr int EPG   = 2048;    // edges per graph
static constexpr int NGR   = 32;      // graphs
static constexpr int NF    = 8;       // filtrations
static constexpr int FEAT  = 512;
static constexpr int ODIM  = 64;
static constexpr int ETOT  = NGR * EPG;

typedef short bf16x8 __attribute__((ext_vector_type(8)));
typedef float f32x4  __attribute__((ext_vector_type(4)));

// order-preserving float -> uint key
__device__ __forceinline__ unsigned int fsort(float f) {
    unsigned int u = __float_as_uint(f);
    return (u & 0x80000000u) ? ~u : (u | 0x80000000u);
}

// split two f32 into packed bf16-hi pair and bf16-lo pair (truncation split).
__device__ __forceinline__ void split2(float a, float b, unsigned& hi, unsigned& lo) {
    unsigned ua = __float_as_uint(a), ub = __float_as_uint(b);
    hi = (ua >> 16) | (ub & 0xffff0000u);
    float ra = a - __uint_as_float(ua & 0xffff0000u);
    float rb = b - __uint_as_float(ub & 0xffff0000u);
    lo = (__float_as_uint(ra) >> 16) | (__float_as_uint(rb) & 0xffff0000u);
}

// ========== 0. W1 -> transposed, split (hi/lo bf16), tile-swizzled ==========
__global__ __launch_bounds__(256) void w1swz_k(
        const float* __restrict__ W1,
        unsigned short* __restrict__ Whi, unsigned short* __restrict__ Wlo) {
    __shared__ float T[64][65];
    const int tid = threadIdx.x;
    const int kb = blockIdx.x >> 3, cb = blockIdx.x & 7;
    const int r16 = tid >> 4, c4 = tid & 15;
#pragma unroll
    for (int p = 0; p < 4; ++p) {
        int kl = r16 + p * 16;
        *(float4*)&T[kl][c4 * 4] = *(const float4*)&W1[(size_t)(kb * 64 + kl) * FEAT + cb * 64 + c4 * 4];
    }
    __syncthreads();
    const int col_l = tid >> 2;
    const int col = cb * 64 + col_l;
    const int sw = (col + (col >> 2)) & 3;
#pragma unroll
    for (int q = 0; q < 2; ++q) {
        int ch = (tid & 3) + q * 4;
        int ktl = ch >> 2, slot = ch & 3;
        int koff = slot ^ sw;
        unsigned hi[4], lo[4];
#pragma unroll
        for (int pj = 0; pj < 4; ++pj) {
            float a = T[ktl * 32 + koff * 8 + pj * 2 + 0][col_l];
            float b = T[ktl * 32 + koff * 8 + pj * 2 + 1][col_l];
            split2(a, b, hi[pj], lo[pj]);
        }
        size_t o = (size_t)col * 512 + (size_t)kb * 64 + ktl * 32 + slot * 8;
        *(uint4*)&Whi[o] = make_uint4(hi[0], hi[1], hi[2], hi[3]);
        *(uint4*)&Wlo[o] = make_uint4(lo[0], lo[1], lo[2], lo[3]);
    }
}

// ========== 1a. split-bf16 MFMA GEMM fused with relu+b1 then @W2 ==========
__global__ __launch_bounds__(256, 2) void mfma_fv_k(
        const float* __restrict__ x, const unsigned short* __restrict__ Whi,
        const unsigned short* __restrict__ Wlo, const float* __restrict__ b1,
        const float* __restrict__ W2, float* __restrict__ fvpart) {
    __shared__ unsigned short AsHi[4096], AsLo[4096], BsHi[4096], BsLo[4096];
    __shared__ float W2s[128][8];
    __shared__ float b1s[128];

    const int tid = threadIdx.x;
    const int lane = tid & 63, wid = tid >> 6;
    const int wr = wid >> 1, wc = wid & 1;
    const int b = blockIdx.x;
    const int rb = (b & 7) * 32 + (b >> 5);
    const int cb = (b >> 3) & 3;
    const int rowBase = rb * 128, colBase = cb * 128;

    for (int i = tid; i < 1024; i += 256)
        W2s[i >> 3][i & 7] = W2[(size_t)(colBase + (i >> 3)) * NF + (i & 7)];
    if (tid < 128) b1s[tid] = b1[colBase + tid];

    const int arow = tid >> 1, ah2 = tid & 1;
    const int aswz = (arow + (arow >> 2)) & 3;
    const float* xp = x + (size_t)(rowBase + arow) * FEAT + ah2 * 16;
    const int bcol = tid >> 1;
    const size_t bsrc = (size_t)(colBase + bcol) * 512 + (size_t)(tid & 1) * 16;
    const int bdst = bcol * 32 + (tid & 1) * 16;

    f32x4 acc[4][4];
#pragma unroll
    for (int m = 0; m < 4; ++m)
#pragma unroll
        for (int n = 0; n < 4; ++n) acc[m][n] = (f32x4){0.f, 0.f, 0.f, 0.f};

    float4 av[4];
    uint4 bhv[2], blv[2];
    av[0] = ((const float4*)xp)[0]; av[1] = ((const float4*)xp)[1];
    av[2] = ((const float4*)xp)[2]; av[3] = ((const float4*)xp)[3];
    bhv[0] = *(const uint4*)(Whi + bsrc); bhv[1] = *(const uint4*)(Whi + bsrc + 8);
    blv[0] = *(const uint4*)(Wlo + bsrc); blv[1] = *(const uint4*)(Wlo + bsrc + 8);

    for (int tk = 0; tk < 16; ++tk) {
        __syncthreads();
#pragma unroll
        for (int cj = 0; cj < 2; ++cj) {
            int koff = ah2 * 2 + cj;
            int slot = koff ^ aswz;
            unsigned h0, h1, h2, h3, l0, l1, l2, l3;
            split2(av[cj * 2 + 0].x, av[cj * 2 + 0].y, h0, l0);
            split2(av[cj * 2 + 0].z, av[cj * 2 + 0].w, h1, l1);
            split2(av[cj * 2 + 1].x, av[cj * 2 + 1].y, h2, l2);
            split2(av[cj * 2 + 1].z, av[cj * 2 + 1].w, h3, l3);
            int o = arow * 32 + slot * 8;
            *(uint4*)&AsHi[o] = make_uint4(h0, h1, h2, h3);
            *(uint4*)&AsLo[o] = make_uint4(l0, l1, l2, l3);
        }
        *(uint4*)&BsHi[bdst] = bhv[0]; *(uint4*)&BsHi[bdst + 8] = bhv[1];
        *(uint4*)&BsLo[bdst] = blv[0]; *(uint4*)&BsLo[bdst + 8] = blv[1];
        if (tk < 15) {
            const float* xq = xp + (tk + 1) * 32;
            av[0] = ((const float4*)xq)[0]; av[1] = ((const float4*)xq)[1];
            av[2] = ((const float4*)xq)[2]; av[3] = ((const float4*)xq)[3];
            const unsigned short* bh = Whi + bsrc + (size_t)(tk + 1) * 32;
            const unsigned short* bl = Wlo + bsrc + (size_t)(tk + 1) * 32;
            bhv[0] = *(const uint4*)bh; bhv[1] = *(const uint4*)(bh + 8);
            blv[0] = *(const uint4*)bl; blv[1] = *(const uint4*)(bl + 8);
        }
        __syncthreads();
        bf16x8 fa[4], fb[4], f2[4];
#pragma unroll
        for (int m = 0; m < 4; ++m) {
            int r = wr * 64 + m * 16 + (lane & 15);
            int slot = (lane >> 4) ^ ((r + (r >> 2)) & 3);
            fa[m] = *(const bf16x8*)&AsHi[r * 32 + slot * 8];
        }
#pragma unroll
        for (int n = 0; n < 4; ++n) {
            int c = wc * 64 + n * 16 + (lane & 15);
            int slot = (lane >> 4) ^ ((c + (c >> 2)) & 3);
            fb[n] = *(const bf16x8*)&BsHi[c * 32 + slot * 8];
        }
#pragma unroll
        for (int m = 0; m < 4; ++m)
#pragma unroll
            for (int n = 0; n < 4; ++n)
                acc[m][n] = __builtin_amdgcn_mfma_f32_16x16x32_bf16(fa[m], fb[n], acc[m][n], 0, 0, 0);
#pragma unroll
        for (int n = 0; n < 4; ++n) {
            int c = wc * 64 + n * 16 + (lane & 15);
            int slot = (lane >> 4) ^ ((c + (c >> 2)) & 3);
            f2[n] = *(const bf16x8*)&BsLo[c * 32 + slot * 8];
        }
#pragma unroll
        for (int m = 0; m < 4; ++m)
#pragma unroll
            for (int n = 0; n < 4; ++n)
                acc[m][n] = __builtin_amdgcn_mfma_f32_16x16x32_bf16(fa[m], f2[n], acc[m][n], 0, 0, 0);
#pragma unroll
        for (int m = 0; m < 4; ++m) {
            int r = wr * 64 + m * 16 + (lane & 15);
            int slot = (lane >> 4) ^ ((r + (r >> 2)) & 3);
            f2[m] = *(const bf16x8*)&AsLo[r * 32 + slot * 8];
        }
#pragma unroll
        for (int m = 0; m < 4; ++m)
#pragma unroll
            for (int n = 0; n < 4; ++n)
                acc[m][n] = __builtin_amdgcn_mfma_f32_16x16x32_bf16(f2[m], fb[n], acc[m][n], 0, 0, 0);
    }

    const int p = cb * 2 + wc;
#pragma unroll
    for (int m = 0; m < 4; ++m) {
        float pf[4][8];
#pragma unroll
        for (int r = 0; r < 4; ++r)
#pragma unroll
            for (int j = 0; j < 8; ++j) pf[r][j] = 0.f;
#pragma unroll
        for (int n = 0; n < 4; ++n) {
            int c = wc * 64 + n * 16 + (lane & 15);
            float bc = b1s[c];
            float4 wA = *(const float4*)&W2s[c][0];
            float4 wB = *(const float4*)&W2s[c][4];
#pragma unroll
            for (int r = 0; r < 4; ++r) {
                float h = fmaxf(acc[m][n][r] + bc, 0.f);
                pf[r][0] += h * wA.x; pf[r][1] += h * wA.y; pf[r][2] += h * wA.z; pf[r][3] += h * wA.w;
                pf[r][4] += h * wB.x; pf[r][5] += h * wB.y; pf[r][6] += h * wB.z; pf[r][7] += h * wB.w;
            }
        }
#pragma unroll
        for (int mask = 1; mask <= 8; mask <<= 1)
#pragma unroll
            for (int r = 0; r < 4; ++r)
#pragma unroll
                for (int j = 0; j < 8; ++j) pf[r][j] += __shfl_xor(pf[r][j], mask);
        if ((lane & 15) == 0) {
            int rowb = rowBase + wr * 64 + m * 16 + (lane >> 4) * 4;
#pragma unroll
            for (int r = 0; r < 4; ++r) {
                *(float4*)&fvpart[(((size_t)p << 15) + rowb + r) * NF + 0] =
                    make_float4(pf[r][0], pf[r][1], pf[r][2], pf[r][3]);
                *(float4*)&fvpart[(((size_t)p << 15) + rowb + r) * NF + 4] =
                    make_float4(pf[r][4], pf[r][5], pf[r][6], pf[r][7]);
            }
        }
    }
}

// ========== 1b. fv = sum of 8 panels + b2; writes fv [N][8] and fvT [8][N] ==========
__global__ __launch_bounds__(256) void fvred_k(
        const float* __restrict__ fvpart, const float* __restrict__ b2,
        float* __restrict__ fv, float* __restrict__ fvT) {
    const int row = blockIdx.x * 256 + threadIdx.x;
    float s[8];
    *(float4*)&s[0] = *(const float4*)&b2[0];
    *(float4*)&s[4] = *(const float4*)&b2[4];
#pragma unroll
    for (int p = 0; p < 8; ++p) {
        float4 lo = *(const float4*)&fvpart[(((size_t)p << 15) + row) * NF + 0];
        float4 hi = *(const float4*)&fvpart[(((size_t)p << 15) + row) * NF + 4];
        s[0] += lo.x; s[1] += lo.y; s[2] += lo.z; s[3] += lo.w;
        s[4] += hi.x; s[5] += hi.y; s[6] += hi.z; s[7] += hi.w;
    }
    *(float4*)&fv[(size_t)row * NF + 0] = *(float4*)&s[0];
    *(float4*)&fv[(size_t)row * NF + 4] = *(float4*)&s[4];
#pragma unroll
    for (int j = 0; j < 8; ++j) fvT[(size_t)j * NN + row] = s[j];
}

// ============ 2a. per-(graph,filtration) edge key build + bitonic sort ============
__global__ __launch_bounds__(512) void uf_sort_k(
        const float* __restrict__ fvT, const int* __restrict__ ei,
        unsigned int* __restrict__ suvw) {
    __shared__ float fvl[NPG];
    __shared__ unsigned long long keys[EPG];
    __shared__ unsigned int uvw[EPG];
    const int tid = threadIdx.x;
    const int g = blockIdx.x >> 3, k = blockIdx.x & 7;

    for (int i = tid; i < NPG; i += 512) fvl[i] = fvT[(size_t)k * NN + (g << 10) + i];
    __syncthreads();
    for (int e = tid; e < EPG; e += 512) {
        int eg = g * EPG + e;
        int u = ei[eg] & (NPG - 1);
        int v = ei[ETOT + eg] & (NPG - 1);
        unsigned int fku = fsort(fvl[u]);
        unsigned int fkv = fsort(fvl[v]);
        unsigned int wfl = (fku > fkv || (fku == fkv && u >= v)) ? 1u : 0u;
        unsigned int fe = fku > fkv ? fku : fkv;
        uvw[e] = (unsigned)u | ((unsigned)v << 10) | (wfl << 20);
        keys[e] = ((unsigned long long)fe << 32) | (unsigned)e;
    }
    for (int size = 2; size <= EPG; size <<= 1) {
        for (int stride = size >> 1; stride > 0; stride >>= 1) {
            __syncthreads();
            for (int i = tid; i < EPG; i += 512) {
                int j = i ^ stride;
                if (j > i) {
                    unsigned long long a = keys[i], b = keys[j];
                    bool asc = (i & size) == 0;
                    if (asc ? (a > b) : (a < b)) { keys[i] = b; keys[j] = a; }
                }
            }
        }
    }
    __syncthreads();
    for (int i = tid; i < EPG; i += 512)
        suvw[(size_t)blockIdx.x * EPG + i] = uvw[(unsigned)(keys[i] & 0xffffffffULL)];
}

// ============ 2b. EXACT sequential union-find at wave speed (round-14, validated) ============
// grid 256 blocks, 256 threads (staging + output); wave 0 executes the merge.
// node word: [fkey:32 | birth_idx:16 | parent:16]. UNION-BY-ELDER: young root
// links under elder root; elder root's record is invariant.
// Serial ballot-commit with LDS writes deferred to window end; 3-shfl
// broadcast {rY|rE, wE}; lanes patch roots/records in registers.
__global__ __launch_bounds__(256) void uf_merge_k(
        const float* __restrict__ fvT, const unsigned int* __restrict__ suvw,
        float* __restrict__ dvT) {
    __shared__ float fvl[NPG];
    __shared__ unsigned long long node[NPG];
    __shared__ unsigned short deathl[NPG];
    __shared__ unsigned int se[EPG];

    const int tid = threadIdx.x;
    const int g = blockIdx.x >> 3, k = blockIdx.x & 7;

    for (int i = tid; i < NPG; i += 256) {
        float val = fvT[(size_t)k * NN + (g << 10) + i];
        fvl[i] = val;
        node[i] = ((unsigned long long)fsort(val) << 32) | ((unsigned long long)(unsigned)i << 16) | (unsigned)i;
        deathl[i] = (unsigned short)i;
    }
    for (int i = tid; i < EPG / 4; i += 256)
        ((uint4*)se)[i] = ((const uint4*)(suvw + (size_t)blockIdx.x * EPG))[i];
    __syncthreads();

    if (tid < 64) {
        const int lane = tid;
        volatile unsigned int* vn32 = (volatile unsigned int*)node;
        volatile unsigned long long* vn64 = (volatile unsigned long long*)node;
        for (int w = 0; w < EPG / 64; ++w) {
            unsigned int pk = se[w * 64 + lane];
            int u = (int)(pk & 1023u), v = (int)((pk >> 10) & 1023u);
            int wd = ((pk >> 20) & 1u) ? u : v;       // death vertex (static)
            // chase with path-halving (low-dword writes preserve birth bits)
            int ru = u;
            {
                unsigned int lw = vn32[ru * 2];
                int p = (int)(lw & 0xffffu);
                while (p != ru) {
                    unsigned int lw2 = vn32[p * 2];
                    int gp = (int)(lw2 & 0xffffu);
                    if (gp != p) vn32[ru * 2] = (lw & 0xffff0000u) | (unsigned)gp;
                    ru = p; lw = lw2; p = gp;
                }
            }
            int rv = v;
            {
                unsigned int lw = vn32[rv * 2];
                int p = (int)(lw & 0xffffu);
                while (p != rv) {
                    unsigned int lw2 = vn32[p * 2];
                    int gp = (int)(lw2 & 0xffffu);
                    if (gp != p) vn32[rv * 2] = (lw & 0xffff0000u) | (unsigned)gp;
                    rv = p; lw = lw2; p = gp;
                }
            }
            unsigned long long wa = vn64[ru];
            unsigned long long wb = vn64[rv];
            bool aliveF = (ru != rv);
            bool committed = false;
            int cY = 0, cE = 0;
            unsigned long long cW = 0;
            unsigned long long mask = __ballot(aliveF);
            while (mask) {
                int li = (int)__builtin_ctzll(mask);   // lowest alive lane = sorted order
                bool uE = (wa >> 16) <= (wb >> 16);
                int rE_l = uE ? ru : rv;
                int rY_l = uE ? rv : ru;
                unsigned long long wE_l = uE ? wa : wb;
                unsigned long long wY_l = uE ? wb : wa;
                unsigned pk2 = (unsigned)rY_l | ((unsigned)rE_l << 10);
                unsigned bpk = __shfl(pk2, li);
                unsigned belo = __shfl((unsigned)wE_l, li);
                unsigned behi = __shfl((unsigned)(wE_l >> 32), li);
                unsigned long long bwE = ((unsigned long long)behi << 32) | belo;
                int brY = (int)(bpk & 1023u), brE = (int)((bpk >> 10) & 1023u);
                if (lane == li) { committed = true; cY = rY_l; cE = rE_l; cW = wY_l; }
                if (ru == brY) { ru = brE; wa = bwE; }
                if (rv == brY) { rv = brE; wb = bwE; }
                aliveF = aliveF && (lane > li) && (ru != rv);
                mask = __ballot(aliveF);
            }
            // flush: disjoint young-root links + death records
            if (committed) {
                deathl[(int)((cW >> 16) & 0xffffu)] = (unsigned short)wd;
                vn64[cY] = (cW & ~0xffffULL) | (unsigned)cE;
            }
            __builtin_amdgcn_wave_barrier();
        }
    }
    __syncthreads();
    for (int i = tid; i < NPG; i += 256)
        dvT[(size_t)k * NN + (g << 10) + i] = fvl[deathl[i]];
}

// ================= 3. h0 = relu(x0 @ W_in + b_in), x0 = interleave(fv,dvT) =================
__global__ __launch_bounds__(256, 2) void feat_k(
        const float* __restrict__ fv, const float* __restrict__ dvT,
        const float* __restrict__ W_in, const float* __restrict__ b_in,
        float* __restrict__ h0) {
    __shared__ float Ws[16][64];
    __shared__ float bs[64];
    const int tid = threadIdx.x;
    for (int i = tid; i < 1024; i += 256) Ws[i >> 6][i & 63] = W_in[i];
    if (tid < 64) bs[tid] = b_in[tid];
    __syncthreads();
    const int n = blockIdx.x * 256 + tid;
    float4 f0 = *(const float4*)&fv[(size_t)n * NF + 0];
    float4 f1 = *(const float4*)&fv[(size_t)n * NF + 4];
    float dd[8];
#pragma unroll
    for (int j = 0; j < 8; ++j) dd[j] = dvT[(size_t)j * NN + n];
    float x0[16] = { f0.x, dd[0], f0.y, dd[1], f0.z, dd[2], f0.w, dd[3],
                     f1.x, dd[4], f1.y, dd[5], f1.z, dd[6], f1.w, dd[7] };
    float out[64];
#pragma unroll
    for (int j = 0; j < 64; ++j) out[j] = bs[j];
#pragma unroll
    for (int i = 0; i < 16; ++i) {
        float a = x0[i];
#pragma unroll
        for (int j4 = 0; j4 < 16; ++j4) {
            float4 w = *(const float4*)&Ws[i][j4 * 4];
            out[j4 * 4 + 0] += a * w.x; out[j4 * 4 + 1] += a * w.y;
            out[j4 * 4 + 2] += a * w.z; out[j4 * 4 + 3] += a * w.w;
        }
    }
#pragma unroll
    for (int j4 = 0; j4 < 16; ++j4) {
        float4 o = { fmaxf(out[j4 * 4 + 0], 0.f), fmaxf(out[j4 * 4 + 1], 0.f),
                     fmaxf(out[j4 * 4 + 2], 0.f), fmaxf(out[j4 * 4 + 3], 0.f) };
        *(float4*)&h0[(size_t)n * 64 + j4 * 4] = o;
    }
}

// ===== 4. fused per-graph column sums + bias[g][j] = Gb[j] - (s[g]/1024)@LW =====
__global__ void redlam_k(const float* __restrict__ h, const float* __restrict__ LW,
                         const float* __restrict__ Gb, float* __restrict__ bias, int Fout) {
    __shared__ float part[4][64];
    __shared__ float sg[64];
    const int tid = threadIdx.x, g = blockIdx.x;
    const int c = tid & 63, rg = tid >> 6;
    float acc = 0.f;
    for (int r = rg; r < NPG; r += 4) acc += h[(size_t)(g * NPG + r) * 64 + c];
    part[rg][c] = acc;
    __syncthreads();
    if (tid < 64) sg[tid] = (part[0][tid] + part[1][tid] + part[2][tid] + part[3][tid]) * (1.0f / 1024.0f);
    __syncthreads();
    for (int j = tid; j < Fout; j += 256) {
        float a = 0.f;
        for (int i = 0; i < 64; ++i) a += sg[i] * LW[i * Fout + j];
        bias[g * Fout + j] = Gb[j] - a;
    }
}

// ================= 6. h1 = relu(h0 @ g1W + bias1[g]) =================
__global__ __launch_bounds__(256, 2) void ds1_k(
        const float* __restrict__ h0, const float* __restrict__ g1W,
        const float* __restrict__ bias1, float* __restrict__ h1) {
    __shared__ float Ws[64][64];
    const int tid = threadIdx.x;
    for (int i = tid; i < 4096; i += 256) Ws[i >> 6][i & 63] = g1W[i];
    __syncthreads();
    const int n = blockIdx.x * 256 + tid;
    const int g = n >> 10;
    float in[64];
#pragma unroll
    for (int i4 = 0; i4 < 16; ++i4) {
        float4 t = *(const float4*)&h0[(size_t)n * 64 + i4 * 4];
        in[i4 * 4 + 0] = t.x; in[i4 * 4 + 1] = t.y; in[i4 * 4 + 2] = t.z; in[i4 * 4 + 3] = t.w;
    }
    float out[64];
#pragma unroll
    for (int j4 = 0; j4 < 16; ++j4) {
        float4 b = *(const float4*)&bias1[g * 64 + j4 * 4];
        out[j4 * 4 + 0] = b.x; out[j4 * 4 + 1] = b.y; out[j4 * 4 + 2] = b.z; out[j4 * 4 + 3] = b.w;
    }
#pragma unroll 8
    for (int i = 0; i < 64; ++i) {
        float a = in[i];
#pragma unroll
        for (int j4 = 0; j4 < 16; ++j4) {
            float4 w = *(const float4*)&Ws[i][j4 * 4];
            out[j4 * 4 + 0] += a * w.x; out[j4 * 4 + 1] += a * w.y;
            out[j4 * 4 + 2] += a * w.z; out[j4 * 4 + 3] += a * w.w;
        }
    }
#pragma unroll
    for (int j4 = 0; j4 < 16; ++j4) {
        float4 o = { fmaxf(out[j4 * 4 + 0], 0.f), fmaxf(out[j4 * 4 + 1], 0.f),
                     fmaxf(out[j4 * 4 + 2], 0.f), fmaxf(out[j4 * 4 + 3], 0.f) };
        *(float4*)&h1[(size_t)n * 64 + j4 * 4] = o;
    }
}

// ===== 7. r = relu(h1 @ g2W + bias2[g]) -> d_out, fused BN partial stats =====
// Per block (32 rows), per 64-col chunk: shfl-reduce rows -> per-block column
// sums/sumsq written to psum/psq in TRANSPOSED [col][block] layout so the
// final reduction reads coalesced.
__global__ __launch_bounds__(256, 2) void ds2_k(
        const float* __restrict__ h1, const float* __restrict__ g2W,
        const float* __restrict__ bias2, float* __restrict__ rout,
        float* __restrict__ psum, float* __restrict__ psq) {
    __shared__ float Ht[32][68];
    __shared__ float Wt[64][68];
    __shared__ float smS[4][64];
    __shared__ float smQ[4][64];
    const int tid = threadIdx.x;
    const int lane = tid & 63, wvid = tid >> 6;
    const int b = blockIdx.x;
    const int rowBase = b * 32;
    const int g = rowBase >> 10;
#pragma unroll
    for (int p = 0; p < 2; ++p) {
        int fid = tid + p * 256;
        int r = fid >> 4, c4 = fid & 15;
        *(float4*)&Ht[r][c4 * 4] = *(const float4*)&h1[(size_t)(rowBase + r) * 64 + c4 * 4];
    }
    const int cg = tid & 15, rg = tid >> 4;
    for (int nc = 0; nc < 8; ++nc) {
        __syncthreads();
#pragma unroll
        for (int p = 0; p < 4; ++p) {
            int fid = tid + p * 256;
            int kk = fid >> 4, c4 = fid & 15;
            *(float4*)&Wt[kk][c4 * 4] = *(const float4*)&g2W[(size_t)kk * FEAT + nc * 64 + c4 * 4];
        }
        __syncthreads();
        float a0[4] = {0.f, 0.f, 0.f, 0.f}, a1[4] = {0.f, 0.f, 0.f, 0.f};
#pragma unroll 8
        for (int kk = 0; kk < 64; ++kk) {
            float h0v = Ht[rg * 2][kk], h1v = Ht[rg * 2 + 1][kk];
            float4 w = *(const float4*)&Wt[kk][cg * 4];
            a0[0] += h0v * w.x; a0[1] += h0v * w.y; a0[2] += h0v * w.z; a0[3] += h0v * w.w;
            a1[0] += h1v * w.x; a1[1] += h1v * w.y; a1[2] += h1v * w.z; a1[3] += h1v * w.w;
        }
        float4 bv = *(const float4*)&bias2[g * FEAT + nc * 64 + cg * 4];
        float r0[4], r1[4];
        r0[0] = fmaxf(a0[0] + bv.x, 0.f); r0[1] = fmaxf(a0[1] + bv.y, 0.f);
        r0[2] = fmaxf(a0[2] + bv.z, 0.f); r0[3] = fmaxf(a0[3] + bv.w, 0.f);
        r1[0] = fmaxf(a1[0] + bv.x, 0.f); r1[1] = fmaxf(a1[1] + bv.y, 0.f);
        r1[2] = fmaxf(a1[2] + bv.z, 0.f); r1[3] = fmaxf(a1[3] + bv.w, 0.f);
        int row0 = rowBase + rg * 2;
        *(float4*)&rout[(size_t)row0 * FEAT + nc * 64 + cg * 4] =
            make_float4(r0[0], r0[1], r0[2], r0[3]);
        *(float4*)&rout[(size_t)(row0 + 1) * FEAT + nc * 64 + cg * 4] =
            make_float4(r1[0], r1[1], r1[2], r1[3]);
        // fused BN partials: reduce the block's 32 rows per column
        float s4[4], q4[4];
#pragma unroll
        for (int j = 0; j < 4; ++j) {
            s4[j] = r0[j] + r1[j];
            q4[j] = r0[j] * r0[j] + r1[j] * r1[j];
        }
#pragma unroll
        for (int j = 0; j < 4; ++j) {
            s4[j] += __shfl_xor(s4[j], 16); q4[j] += __shfl_xor(q4[j], 16);
            s4[j] += __shfl_xor(s4[j], 32); q4[j] += __shfl_xor(q4[j], 32);
        }
        if (lane < 16) {
#pragma unroll
            for (int j = 0; j < 4; ++j) {
                smS[wvid][lane * 4 + j] = s4[j];
                smQ[wvid][lane * 4 + j] = q4[j];
            }
        }
        __syncthreads();
        if (tid < 64) {
            float ss = smS[0][tid] + smS[1][tid] + smS[2][tid] + smS[3][tid];
            float qq = smQ[0][tid] + smQ[1][tid] + smQ[2][tid] + smQ[3][tid];
            psum[(size_t)(nc * 64 + tid) * 1024 + b] = ss;
            psq [(size_t)(nc * 64 + tid) * 1024 + b] = qq;
        }
    }
}

// ===== 8. BN scale/shift from per-block partials (transposed [col][block]) =====
__global__ void bnst2_k(const float* __restrict__ psum, const float* __restrict__ psq,
                        const float* __restrict__ gamma, const float* __restrict__ beta,
                        float* __restrict__ scsh) {
    __shared__ float wS[4], wQ[4];
    const int c = blockIdx.x;        // 512 blocks, one column each
    const int tid = threadIdx.x;     // 256 threads
    float s = psum[(size_t)c * 1024 + tid] + psum[(size_t)c * 1024 + 256 + tid]
            + psum[(size_t)c * 1024 + 512 + tid] + psum[(size_t)c * 1024 + 768 + tid];
    float q = psq[(size_t)c * 1024 + tid] + psq[(size_t)c * 1024 + 256 + tid]
            + psq[(size_t)c * 1024 + 512 + tid] + psq[(size_t)c * 1024 + 768 + tid];
#pragma unroll
    for (int m = 1; m <= 32; m <<= 1) { s += __shfl_xor(s, m); q += __shfl_xor(q, m); }
    if ((tid & 63) == 0) { wS[tid >> 6] = s; wQ[tid >> 6] = q; }
    __syncthreads();
    if (tid == 0) {
        float S = wS[0] + wS[1] + wS[2] + wS[3];
        float Q = wQ[0] + wQ[1] + wQ[2] + wQ[3];
        float mu = S * (1.0f / (float)NN);
        float var = Q * (1.0f / (float)NN) - mu * mu;
        float sc = gamma[c] * rsqrtf(var + 1e-5f);
        scsh[c] = sc;
        scsh[FEAT + c] = beta[c] - mu * sc;
    }
}

// ================= 9. out = x + r*scale + shift (in-place on d_out) =================
__global__ void final_k(const float* __restrict__ x, const float* __restrict__ scsh,
                        float* __restrict__ out) {
    const int total4 = NN * (FEAT / 4);
    for (int idx = blockIdx.x * 256 + threadIdx.x; idx < total4; idx += 2048 * 256) {
        int col4 = idx & (FEAT / 4 - 1);
        float4 rv = *(float4*)&out[(size_t)idx * 4];
        float4 xv = *(const float4*)&x[(size_t)idx * 4];
        float4 sc = *(const float4*)&scsh[col4 * 4];
        float4 sh = *(const float4*)&scsh[FEAT + col4 * 4];
        float4 o = { xv.x + rv.x * sc.x + sh.x, xv.y + rv.y * sc.y + sh.y,
                     xv.z + rv.z * sc.z + sh.z, xv.w + rv.w * sc.w + sh.w };
        *(float4*)&out[(size_t)idx * 4] = o;
    }
}

// =============================== launcher ===============================
extern "C" void kernel_launch(void* const* d_in, const int* in_sizes, int n_in,
                              void* d_out, int out_size, void* d_ws, size_t ws_size,
                              hipStream_t stream) {
    const float* x     = (const float*)d_in[0];
    const int*   ei    = (const int*)d_in[1];
    const float* W1    = (const float*)d_in[5];
    const float* b1    = (const float*)d_in[6];
    const float* W2    = (const float*)d_in[7];
    const float* b2    = (const float*)d_in[8];
    const float* W_in  = (const float*)d_in[9];
    const float* b_in  = (const float*)d_in[10];
    const float* g1W   = (const float*)d_in[11];
    const float* g1b   = (const float*)d_in[12];
    const float* l1W   = (const float*)d_in[13];
    const float* g2W   = (const float*)d_in[14];
    const float* g2b   = (const float*)d_in[15];
    const float* l2W   = (const float*)d_in[16];
    const float* gamma = (const float*)d_in[17];
    const float* beta  = (const float*)d_in[18];
    float* out = (float*)d_out;
    float* ws  = (float*)d_ws;

    float* fv    = ws;                 // [0, 262144)
    float* dvT   = ws + 262144;        // [262144, 524288)  (col-major [8][N])
    float* h0    = ws + 524288;        // [524288, 2621440)
    float* h1    = ws + 2621440;       // [2621440, 4718592)
    unsigned short* W1hi = (unsigned short*)(ws + 262144);  // aliases dvT (written later)
    unsigned short* W1lo = (unsigned short*)(ws + 393216);
    float*        fvpart = ws + 524288;                     // aliases h0 (dead after fvred)
    float*        fvT  = ws + 2621440;                      // aliases h1 (written later)
    unsigned int* suvw = (unsigned int*)(ws + 2883584);
    // psum/psq [512][1024] alias the h0 region (h0 dead after ds1)
    float* psum  = ws + 524288;        // 524288 floats
    float* psq   = ws + 1048576;       // 524288 floats
    float* bias1 = ws + 4720640;
    float* bias2 = ws + 4724736;
    float* scsh  = ws + 5003264;

    hipLaunchKernelGGL(w1swz_k,    dim3(64),   dim3(256), 0, stream, W1, W1hi, W1lo);
    hipLaunchKernelGGL(mfma_fv_k,  dim3(1024), dim3(256), 0, stream, x, W1hi, W1lo, b1, W2, fvpart);
    hipLaunchKernelGGL(fvred_k,    dim3(128),  dim3(256), 0, stream, fvpart, b2, fv, fvT);
    hipLaunchKernelGGL(uf_sort_k,  dim3(256),  dim3(512), 0, stream, fvT, ei, suvw);
    hipLaunchKernelGGL(uf_merge_k, dim3(256),  dim3(256), 0, stream, fvT, suvw, dvT);
    hipLaunchKernelGGL(feat_k,     dim3(128),  dim3(256), 0, stream, fv, dvT, W_in, b_in, h0);
    hipLaunchKernelGGL(redlam_k,   dim3(32),   dim3(256), 0, stream, h0, l1W, g1b, bias1, 64);
    hipLaunchKernelGGL(ds1_k,      dim3(128),  dim3(256), 0, stream, h0, g1W, bias1, h1);
    hipLaunchKernelGGL(redlam_k,   dim3(32),   dim3(256), 0, stream, h1, l2W, g2b, bias2, 512);
    hipLaunchKernelGGL(ds2_k,      dim3(1024), dim3(256), 0, stream, h1, g2W, bias2, out, psum, psq);
    hipLaunchKernelGGL(bnst2_k,    dim3(512),  dim3(256), 0, stream, psum, psq, gamma, beta, scsh);
    hipLaunchKernelGGL(final_k,    dim3(2048), dim3(256), 0, stream, x, scsh, out);
}

// Round 18
// 594.675 us; speedup vs baseline: 1.3569x; 1.0480x over previous
//
#include <hip/hip_runtime.h>
#include <stdint.h>

// ---------------- problem constants (fixed by setup_inputs) ----------------
static constexpr int NN    = 32768;   // nodes
static constexpr int NPG   = 1024;    // nodes per graph
static constexpr int EPG   = 2048;    // edges per graph
static constexpr int NGR   = 32;      // graphs
static constexpr int NF    = 8;       // filtrations
static constexpr int FEAT  = 512;
static constexpr int ODIM  = 64;
static constexpr int ETOT  = NGR * EPG;

typedef short bf16x8 __attribute__((ext_vector_type(8)));
typedef float f32x4  __attribute__((ext_vector_type(4)));

// order-preserving float -> uint key
__device__ __forceinline__ unsigned int fsort(float f) {
    unsigned int u = __float_as_uint(f);
    return (u & 0x80000000u) ? ~u : (u | 0x80000000u);
}

// split two f32 into packed bf16-hi pair and bf16-lo pair (truncation split).
__device__ __forceinline__ void split2(float a, float b, unsigned& hi, unsigned& lo) {
    unsigned ua = __float_as_uint(a), ub = __float_as_uint(b);
    hi = (ua >> 16) | (ub & 0xffff0000u);
    float ra = a - __uint_as_float(ua & 0xffff0000u);
    float rb = b - __uint_as_float(ub & 0xffff0000u);
    lo = (__float_as_uint(ra) >> 16) | (__float_as_uint(rb) & 0xffff0000u);
}

// ========== 0. W1 -> transposed, split (hi/lo bf16), tile-swizzled ==========
__global__ __launch_bounds__(256) void w1swz_k(
        const float* __restrict__ W1,
        unsigned short* __restrict__ Whi, unsigned short* __restrict__ Wlo) {
    __shared__ float T[64][65];
    const int tid = threadIdx.x;
    const int kb = blockIdx.x >> 3, cb = blockIdx.x & 7;
    const int r16 = tid >> 4, c4 = tid & 15;
#pragma unroll
    for (int p = 0; p < 4; ++p) {
        int kl = r16 + p * 16;
        *(float4*)&T[kl][c4 * 4] = *(const float4*)&W1[(size_t)(kb * 64 + kl) * FEAT + cb * 64 + c4 * 4];
    }
    __syncthreads();
    const int col_l = tid >> 2;
    const int col = cb * 64 + col_l;
    const int sw = (col + (col >> 2)) & 3;
#pragma unroll
    for (int q = 0; q < 2; ++q) {
        int ch = (tid & 3) + q * 4;
        int ktl = ch >> 2, slot = ch & 3;
        int koff = slot ^ sw;
        unsigned hi[4], lo[4];
#pragma unroll
        for (int pj = 0; pj < 4; ++pj) {
            float a = T[ktl * 32 + koff * 8 + pj * 2 + 0][col_l];
            float b = T[ktl * 32 + koff * 8 + pj * 2 + 1][col_l];
            split2(a, b, hi[pj], lo[pj]);
        }
        size_t o = (size_t)col * 512 + (size_t)kb * 64 + ktl * 32 + slot * 8;
        *(uint4*)&Whi[o] = make_uint4(hi[0], hi[1], hi[2], hi[3]);
        *(uint4*)&Wlo[o] = make_uint4(lo[0], lo[1], lo[2], lo[3]);
    }
}

// ========== 1a. split-bf16 MFMA GEMM fused with relu+b1 then @W2 ==========
__global__ __launch_bounds__(256, 2) void mfma_fv_k(
        const float* __restrict__ x, const unsigned short* __restrict__ Whi,
        const unsigned short* __restrict__ Wlo, const float* __restrict__ b1,
        const float* __restrict__ W2, float* __restrict__ fvpart) {
    __shared__ unsigned short AsHi[4096], AsLo[4096], BsHi[4096], BsLo[4096];
    __shared__ float W2s[128][8];
    __shared__ float b1s[128];

    const int tid = threadIdx.x;
    const int lane = tid & 63, wid = tid >> 6;
    const int wr = wid >> 1, wc = wid & 1;
    const int b = blockIdx.x;
    const int rb = (b & 7) * 32 + (b >> 5);
    const int cb = (b >> 3) & 3;
    const int rowBase = rb * 128, colBase = cb * 128;

    for (int i = tid; i < 1024; i += 256)
        W2s[i >> 3][i & 7] = W2[(size_t)(colBase + (i >> 3)) * NF + (i & 7)];
    if (tid < 128) b1s[tid] = b1[colBase + tid];

    const int arow = tid >> 1, ah2 = tid & 1;
    const int aswz = (arow + (arow >> 2)) & 3;
    const float* xp = x + (size_t)(rowBase + arow) * FEAT + ah2 * 16;
    const int bcol = tid >> 1;
    const size_t bsrc = (size_t)(colBase + bcol) * 512 + (size_t)(tid & 1) * 16;
    const int bdst = bcol * 32 + (tid & 1) * 16;

    f32x4 acc[4][4];
#pragma unroll
    for (int m = 0; m < 4; ++m)
#pragma unroll
        for (int n = 0; n < 4; ++n) acc[m][n] = (f32x4){0.f, 0.f, 0.f, 0.f};

    float4 av[4];
    uint4 bhv[2], blv[2];
    av[0] = ((const float4*)xp)[0]; av[1] = ((const float4*)xp)[1];
    av[2] = ((const float4*)xp)[2]; av[3] = ((const float4*)xp)[3];
    bhv[0] = *(const uint4*)(Whi + bsrc); bhv[1] = *(const uint4*)(Whi + bsrc + 8);
    blv[0] = *(const uint4*)(Wlo + bsrc); blv[1] = *(const uint4*)(Wlo + bsrc + 8);

    for (int tk = 0; tk < 16; ++tk) {
        __syncthreads();
#pragma unroll
        for (int cj = 0; cj < 2; ++cj) {
            int koff = ah2 * 2 + cj;
            int slot = koff ^ aswz;
            unsigned h0, h1, h2, h3, l0, l1, l2, l3;
            split2(av[cj * 2 + 0].x, av[cj * 2 + 0].y, h0, l0);
            split2(av[cj * 2 + 0].z, av[cj * 2 + 0].w, h1, l1);
            split2(av[cj * 2 + 1].x, av[cj * 2 + 1].y, h2, l2);
            split2(av[cj * 2 + 1].z, av[cj * 2 + 1].w, h3, l3);
            int o = arow * 32 + slot * 8;
            *(uint4*)&AsHi[o] = make_uint4(h0, h1, h2, h3);
            *(uint4*)&AsLo[o] = make_uint4(l0, l1, l2, l3);
        }
        *(uint4*)&BsHi[bdst] = bhv[0]; *(uint4*)&BsHi[bdst + 8] = bhv[1];
        *(uint4*)&BsLo[bdst] = blv[0]; *(uint4*)&BsLo[bdst + 8] = blv[1];
        if (tk < 15) {
            const float* xq = xp + (tk + 1) * 32;
            av[0] = ((const float4*)xq)[0]; av[1] = ((const float4*)xq)[1];
            av[2] = ((const float4*)xq)[2]; av[3] = ((const float4*)xq)[3];
            const unsigned short* bh = Whi + bsrc + (size_t)(tk + 1) * 32;
            const unsigned short* bl = Wlo + bsrc + (size_t)(tk + 1) * 32;
            bhv[0] = *(const uint4*)bh; bhv[1] = *(const uint4*)(bh + 8);
            blv[0] = *(const uint4*)bl; blv[1] = *(const uint4*)(bl + 8);
        }
        __syncthreads();
        bf16x8 fa[4], fb[4], f2[4];
#pragma unroll
        for (int m = 0; m < 4; ++m) {
            int r = wr * 64 + m * 16 + (lane & 15);
            int slot = (lane >> 4) ^ ((r + (r >> 2)) & 3);
            fa[m] = *(const bf16x8*)&AsHi[r * 32 + slot * 8];
        }
#pragma unroll
        for (int n = 0; n < 4; ++n) {
            int c = wc * 64 + n * 16 + (lane & 15);
            int slot = (lane >> 4) ^ ((c + (c >> 2)) & 3);
            fb[n] = *(const bf16x8*)&BsHi[c * 32 + slot * 8];
        }
#pragma unroll
        for (int m = 0; m < 4; ++m)
#pragma unroll
            for (int n = 0; n < 4; ++n)
                acc[m][n] = __builtin_amdgcn_mfma_f32_16x16x32_bf16(fa[m], fb[n], acc[m][n], 0, 0, 0);
#pragma unroll
        for (int n = 0; n < 4; ++n) {
            int c = wc * 64 + n * 16 + (lane & 15);
            int slot = (lane >> 4) ^ ((c + (c >> 2)) & 3);
            f2[n] = *(const bf16x8*)&BsLo[c * 32 + slot * 8];
        }
#pragma unroll
        for (int m = 0; m < 4; ++m)
#pragma unroll
            for (int n = 0; n < 4; ++n)
                acc[m][n] = __builtin_amdgcn_mfma_f32_16x16x32_bf16(fa[m], f2[n], acc[m][n], 0, 0, 0);
#pragma unroll
        for (int m = 0; m < 4; ++m) {
            int r = wr * 64 + m * 16 + (lane & 15);
            int slot = (lane >> 4) ^ ((r + (r >> 2)) & 3);
            f2[m] = *(const bf16x8*)&AsLo[r * 32 + slot * 8];
        }
#pragma unroll
        for (int m = 0; m < 4; ++m)
#pragma unroll
            for (int n = 0; n < 4; ++n)
                acc[m][n] = __builtin_amdgcn_mfma_f32_16x16x32_bf16(f2[m], fb[n], acc[m][n], 0, 0, 0);
    }

    const int p = cb * 2 + wc;
#pragma unroll
    for (int m = 0; m < 4; ++m) {
        float pf[4][8];
#pragma unroll
        for (int r = 0; r < 4; ++r)
#pragma unroll
            for (int j = 0; j < 8; ++j) pf[r][j] = 0.f;
#pragma unroll
        for (int n = 0; n < 4; ++n) {
            int c = wc * 64 + n * 16 + (lane & 15);
            float bc = b1s[c];
            float4 wA = *(const float4*)&W2s[c][0];
            float4 wB = *(const float4*)&W2s[c][4];
#pragma unroll
            for (int r = 0; r < 4; ++r) {
                float h = fmaxf(acc[m][n][r] + bc, 0.f);
                pf[r][0] += h * wA.x; pf[r][1] += h * wA.y; pf[r][2] += h * wA.z; pf[r][3] += h * wA.w;
                pf[r][4] += h * wB.x; pf[r][5] += h * wB.y; pf[r][6] += h * wB.z; pf[r][7] += h * wB.w;
            }
        }
#pragma unroll
        for (int mask = 1; mask <= 8; mask <<= 1)
#pragma unroll
            for (int r = 0; r < 4; ++r)
#pragma unroll
                for (int j = 0; j < 8; ++j) pf[r][j] += __shfl_xor(pf[r][j], mask);
        if ((lane & 15) == 0) {
            int rowb = rowBase + wr * 64 + m * 16 + (lane >> 4) * 4;
#pragma unroll
            for (int r = 0; r < 4; ++r) {
                *(float4*)&fvpart[(((size_t)p << 15) + rowb + r) * NF + 0] =
                    make_float4(pf[r][0], pf[r][1], pf[r][2], pf[r][3]);
                *(float4*)&fvpart[(((size_t)p << 15) + rowb + r) * NF + 4] =
                    make_float4(pf[r][4], pf[r][5], pf[r][6], pf[r][7]);
            }
        }
    }
}

// ========== 1b. fv = sum of 8 panels + b2; writes fv [N][8] and fvT [8][N] ==========
__global__ __launch_bounds__(256) void fvred_k(
        const float* __restrict__ fvpart, const float* __restrict__ b2,
        float* __restrict__ fv, float* __restrict__ fvT) {
    const int row = blockIdx.x * 256 + threadIdx.x;
    float s[8];
    *(float4*)&s[0] = *(const float4*)&b2[0];
    *(float4*)&s[4] = *(const float4*)&b2[4];
#pragma unroll
    for (int p = 0; p < 8; ++p) {
        float4 lo = *(const float4*)&fvpart[(((size_t)p << 15) + row) * NF + 0];
        float4 hi = *(const float4*)&fvpart[(((size_t)p << 15) + row) * NF + 4];
        s[0] += lo.x; s[1] += lo.y; s[2] += lo.z; s[3] += lo.w;
        s[4] += hi.x; s[5] += hi.y; s[6] += hi.z; s[7] += hi.w;
    }
    *(float4*)&fv[(size_t)row * NF + 0] = *(float4*)&s[0];
    *(float4*)&fv[(size_t)row * NF + 4] = *(float4*)&s[4];
#pragma unroll
    for (int j = 0; j < 8; ++j) fvT[(size_t)j * NN + row] = s[j];
}

// ============ 2a. per-(graph,filtration) edge key build + bitonic sort ============
__global__ __launch_bounds__(512) void uf_sort_k(
        const float* __restrict__ fvT, const int* __restrict__ ei,
        unsigned int* __restrict__ suvw) {
    __shared__ float fvl[NPG];
    __shared__ unsigned long long keys[EPG];
    __shared__ unsigned int uvw[EPG];
    const int tid = threadIdx.x;
    const int g = blockIdx.x >> 3, k = blockIdx.x & 7;

    for (int i = tid; i < NPG; i += 512) fvl[i] = fvT[(size_t)k * NN + (g << 10) + i];
    __syncthreads();
    for (int e = tid; e < EPG; e += 512) {
        int eg = g * EPG + e;
        int u = ei[eg] & (NPG - 1);
        int v = ei[ETOT + eg] & (NPG - 1);
        unsigned int fku = fsort(fvl[u]);
        unsigned int fkv = fsort(fvl[v]);
        unsigned int wfl = (fku > fkv || (fku == fkv && u >= v)) ? 1u : 0u;
        unsigned int fe = fku > fkv ? fku : fkv;
        uvw[e] = (unsigned)u | ((unsigned)v << 10) | (wfl << 20);
        keys[e] = ((unsigned long long)fe << 32) | (unsigned)e;
    }
    for (int size = 2; size <= EPG; size <<= 1) {
        for (int stride = size >> 1; stride > 0; stride >>= 1) {
            __syncthreads();
            for (int i = tid; i < EPG; i += 512) {
                int j = i ^ stride;
                if (j > i) {
                    unsigned long long a = keys[i], b = keys[j];
                    bool asc = (i & size) == 0;
                    if (asc ? (a > b) : (a < b)) { keys[i] = b; keys[j] = a; }
                }
            }
        }
    }
    __syncthreads();
    for (int i = tid; i < EPG; i += 512)
        suvw[(size_t)blockIdx.x * EPG + i] = uvw[(unsigned)(keys[i] & 0xffffffffULL)];
}

// ============ 2b. EXACT sequential union-find at wave speed ============
// grid 256 blocks, 256 threads (staging + output); wave 0 executes the merge.
// node word: [fkey:32 | birth_idx:16 | parent:16]. UNION-BY-ELDER: young root
// links under elder root; elder root's record is invariant.
// Round-14 serial ballot loop with the per-lane elder/young split HOISTED out
// of the loop: {pk2, wE, wY} are computed once after the chase and recomputed
// only by lanes whose roots get patched (rare, exec-guarded). Loop body is
// ctz -> 3 shfls -> 2 compare-patches -> ballot. Committed lane self-retires
// via its own patch (young root -> elder makes ru==rv).
__global__ __launch_bounds__(256) void uf_merge_k(
        const float* __restrict__ fvT, const unsigned int* __restrict__ suvw,
        float* __restrict__ dvT) {
    __shared__ float fvl[NPG];
    __shared__ unsigned long long node[NPG];
    __shared__ unsigned short deathl[NPG];
    __shared__ unsigned int se[EPG];

    const int tid = threadIdx.x;
    const int g = blockIdx.x >> 3, k = blockIdx.x & 7;

    for (int i = tid; i < NPG; i += 256) {
        float val = fvT[(size_t)k * NN + (g << 10) + i];
        fvl[i] = val;
        node[i] = ((unsigned long long)fsort(val) << 32) | ((unsigned long long)(unsigned)i << 16) | (unsigned)i;
        deathl[i] = (unsigned short)i;
    }
    for (int i = tid; i < EPG / 4; i += 256)
        ((uint4*)se)[i] = ((const uint4*)(suvw + (size_t)blockIdx.x * EPG))[i];
    __syncthreads();

    if (tid < 64) {
        const int lane = tid;
        volatile unsigned int* vn32 = (volatile unsigned int*)node;
        volatile unsigned long long* vn64 = (volatile unsigned long long*)node;
        for (int w = 0; w < EPG / 64; ++w) {
            unsigned int pk = se[w * 64 + lane];
            int u = (int)(pk & 1023u), v = (int)((pk >> 10) & 1023u);
            int wd = ((pk >> 20) & 1u) ? u : v;       // death vertex (static)
            // chase with path-halving (low-dword writes preserve birth bits)
            int ru = u;
            {
                unsigned int lw = vn32[ru * 2];
                int p = (int)(lw & 0xffffu);
                while (p != ru) {
                    unsigned int lw2 = vn32[p * 2];
                    int gp = (int)(lw2 & 0xffffu);
                    if (gp != p) vn32[ru * 2] = (lw & 0xffff0000u) | (unsigned)gp;
                    ru = p; lw = lw2; p = gp;
                }
            }
            int rv = v;
            {
                unsigned int lw = vn32[rv * 2];
                int p = (int)(lw & 0xffffu);
                while (p != rv) {
                    unsigned int lw2 = vn32[p * 2];
                    int gp = (int)(lw2 & 0xffffu);
                    if (gp != p) vn32[rv * 2] = (lw & 0xffff0000u) | (unsigned)gp;
                    rv = p; lw = lw2; p = gp;
                }
            }
            unsigned long long wa = vn64[ru];
            unsigned long long wb = vn64[rv];
            bool aliveF = (ru != rv);
            // hoisted per-lane elder/young split ((x&~0xffff) compare == (x>>16) compare)
            bool uE = (wa & ~0xffffULL) <= (wb & ~0xffffULL);
            int rY_l = uE ? rv : ru;
            unsigned long long wE_l = uE ? wa : wb;
            unsigned long long wY_l = uE ? wb : wa;
            unsigned pk2 = (unsigned)rY_l | ((unsigned)(uE ? ru : rv) << 10);
            bool committed = false;
            int cY = 0, cE = 0;
            unsigned long long cW = 0;
            unsigned long long mask = __ballot(aliveF);
            while (mask) {
                int li = (int)__builtin_ctzll(mask);   // lowest alive lane = sorted order
                unsigned bpk = __shfl(pk2, li);
                unsigned belo = __shfl((unsigned)wE_l, li);
                unsigned behi = __shfl((unsigned)(wE_l >> 32), li);
                unsigned long long bwE = ((unsigned long long)behi << 32) | belo;
                int brY = (int)(bpk & 1023u), brE = (int)((bpk >> 10) & 1023u);
                if (lane == li) { committed = true; cY = rY_l; cE = brE; cW = wY_l; }
                bool p0 = (ru == brY), p1 = (rv == brY);
                if (p0) { ru = brE; wa = bwE; }
                if (p1) { rv = brE; wb = bwE; }
                aliveF = aliveF && (ru != rv);
                if ((p0 || p1) && aliveF) {            // rare: recompute hoisted values
                    uE = (wa & ~0xffffULL) <= (wb & ~0xffffULL);
                    rY_l = uE ? rv : ru;
                    wE_l = uE ? wa : wb;
                    wY_l = uE ? wb : wa;
                    pk2 = (unsigned)rY_l | ((unsigned)(uE ? ru : rv) << 10);
                }
                mask = __ballot(aliveF);
            }
            // flush: disjoint young-root links + death records
            if (committed) {
                deathl[(int)((cW >> 16) & 0xffffu)] = (unsigned short)wd;
                vn64[cY] = (cW & ~0xffffULL) | (unsigned)cE;
            }
            __builtin_amdgcn_wave_barrier();
        }
    }
    __syncthreads();
    for (int i = tid; i < NPG; i += 256)
        dvT[(size_t)k * NN + (g << 10) + i] = fvl[deathl[i]];
}

// ================= 3. h0 = relu(x0 @ W_in + b_in), x0 = interleave(fv,dvT) =================
__global__ __launch_bounds__(256, 2) void feat_k(
        const float* __restrict__ fv, const float* __restrict__ dvT,
        const float* __restrict__ W_in, const float* __restrict__ b_in,
        float* __restrict__ h0) {
    __shared__ float Ws[16][64];
    __shared__ float bs[64];
    const int tid = threadIdx.x;
    for (int i = tid; i < 1024; i += 256) Ws[i >> 6][i & 63] = W_in[i];
    if (tid < 64) bs[tid] = b_in[tid];
    __syncthreads();
    const int n = blockIdx.x * 256 + tid;
    float4 f0 = *(const float4*)&fv[(size_t)n * NF + 0];
    float4 f1 = *(const float4*)&fv[(size_t)n * NF + 4];
    float dd[8];
#pragma unroll
    for (int j = 0; j < 8; ++j) dd[j] = dvT[(size_t)j * NN + n];
    float x0[16] = { f0.x, dd[0], f0.y, dd[1], f0.z, dd[2], f0.w, dd[3],
                     f1.x, dd[4], f1.y, dd[5], f1.z, dd[6], f1.w, dd[7] };
    float out[64];
#pragma unroll
    for (int j = 0; j < 64; ++j) out[j] = bs[j];
#pragma unroll
    for (int i = 0; i < 16; ++i) {
        float a = x0[i];
#pragma unroll
        for (int j4 = 0; j4 < 16; ++j4) {
            float4 w = *(const float4*)&Ws[i][j4 * 4];
            out[j4 * 4 + 0] += a * w.x; out[j4 * 4 + 1] += a * w.y;
            out[j4 * 4 + 2] += a * w.z; out[j4 * 4 + 3] += a * w.w;
        }
    }
#pragma unroll
    for (int j4 = 0; j4 < 16; ++j4) {
        float4 o = { fmaxf(out[j4 * 4 + 0], 0.f), fmaxf(out[j4 * 4 + 1], 0.f),
                     fmaxf(out[j4 * 4 + 2], 0.f), fmaxf(out[j4 * 4 + 3], 0.f) };
        *(float4*)&h0[(size_t)n * 64 + j4 * 4] = o;
    }
}

// ===== 4. fused per-graph column sums + bias[g][j] = Gb[j] - (s[g]/1024)@LW =====
__global__ void redlam_k(const float* __restrict__ h, const float* __restrict__ LW,
                         const float* __restrict__ Gb, float* __restrict__ bias, int Fout) {
    __shared__ float part[4][64];
    __shared__ float sg[64];
    const int tid = threadIdx.x, g = blockIdx.x;
    const int c = tid & 63, rg = tid >> 6;
    float acc = 0.f;
    for (int r = rg; r < NPG; r += 4) acc += h[(size_t)(g * NPG + r) * 64 + c];
    part[rg][c] = acc;
    __syncthreads();
    if (tid < 64) sg[tid] = (part[0][tid] + part[1][tid] + part[2][tid] + part[3][tid]) * (1.0f / 1024.0f);
    __syncthreads();
    for (int j = tid; j < Fout; j += 256) {
        float a = 0.f;
        for (int i = 0; i < 64; ++i) a += sg[i] * LW[i * Fout + j];
        bias[g * Fout + j] = Gb[j] - a;
    }
}

// ================= 6. h1 = relu(h0 @ g1W + bias1[g]) =================
__global__ __launch_bounds__(256, 2) void ds1_k(
        const float* __restrict__ h0, const float* __restrict__ g1W,
        const float* __restrict__ bias1, float* __restrict__ h1) {
    __shared__ float Ws[64][64];
    const int tid = threadIdx.x;
    for (int i = tid; i < 4096; i += 256) Ws[i >> 6][i & 63] = g1W[i];
    __syncthreads();
    const int n = blockIdx.x * 256 + tid;
    const int g = n >> 10;
    float in[64];
#pragma unroll
    for (int i4 = 0; i4 < 16; ++i4) {
        float4 t = *(const float4*)&h0[(size_t)n * 64 + i4 * 4];
        in[i4 * 4 + 0] = t.x; in[i4 * 4 + 1] = t.y; in[i4 * 4 + 2] = t.z; in[i4 * 4 + 3] = t.w;
    }
    float out[64];
#pragma unroll
    for (int j4 = 0; j4 < 16; ++j4) {
        float4 b = *(const float4*)&bias1[g * 64 + j4 * 4];
        out[j4 * 4 + 0] = b.x; out[j4 * 4 + 1] = b.y; out[j4 * 4 + 2] = b.z; out[j4 * 4 + 3] = b.w;
    }
#pragma unroll 8
    for (int i = 0; i < 64; ++i) {
        float a = in[i];
#pragma unroll
        for (int j4 = 0; j4 < 16; ++j4) {
            float4 w = *(const float4*)&Ws[i][j4 * 4];
            out[j4 * 4 + 0] += a * w.x; out[j4 * 4 + 1] += a * w.y;
            out[j4 * 4 + 2] += a * w.z; out[j4 * 4 + 3] += a * w.w;
        }
    }
#pragma unroll
    for (int j4 = 0; j4 < 16; ++j4) {
        float4 o = { fmaxf(out[j4 * 4 + 0], 0.f), fmaxf(out[j4 * 4 + 1], 0.f),
                     fmaxf(out[j4 * 4 + 2], 0.f), fmaxf(out[j4 * 4 + 3], 0.f) };
        *(float4*)&h1[(size_t)n * 64 + j4 * 4] = o;
    }
}

// ===== 7. r = relu(h1 @ g2W + bias2[g]) -> d_out, fused BN partial stats =====
__global__ __launch_bounds__(256, 2) void ds2_k(
        const float* __restrict__ h1, const float* __restrict__ g2W,
        const float* __restrict__ bias2, float* __restrict__ rout,
        float* __restrict__ psum, float* __restrict__ psq) {
    __shared__ float Ht[32][68];
    __shared__ float Wt[64][68];
    __shared__ float smS[4][64];
    __shared__ float smQ[4][64];
    const int tid = threadIdx.x;
    const int lane = tid & 63, wvid = tid >> 6;
    const int b = blockIdx.x;
    const int rowBase = b * 32;
    const int g = rowBase >> 10;
#pragma unroll
    for (int p = 0; p < 2; ++p) {
        int fid = tid + p * 256;
        int r = fid >> 4, c4 = fid & 15;
        *(float4*)&Ht[r][c4 * 4] = *(const float4*)&h1[(size_t)(rowBase + r) * 64 + c4 * 4];
    }
    const int cg = tid & 15, rg = tid >> 4;
    for (int nc = 0; nc < 8; ++nc) {
        __syncthreads();
#pragma unroll
        for (int p = 0; p < 4; ++p) {
            int fid = tid + p * 256;
            int kk = fid >> 4, c4 = fid & 15;
            *(float4*)&Wt[kk][c4 * 4] = *(const float4*)&g2W[(size_t)kk * FEAT + nc * 64 + c4 * 4];
        }
        __syncthreads();
        float a0[4] = {0.f, 0.f, 0.f, 0.f}, a1[4] = {0.f, 0.f, 0.f, 0.f};
#pragma unroll 8
        for (int kk = 0; kk < 64; ++kk) {
            float h0v = Ht[rg * 2][kk], h1v = Ht[rg * 2 + 1][kk];
            float4 w = *(const float4*)&Wt[kk][cg * 4];
            a0[0] += h0v * w.x; a0[1] += h0v * w.y; a0[2] += h0v * w.z; a0[3] += h0v * w.w;
            a1[0] += h1v * w.x; a1[1] += h1v * w.y; a1[2] += h1v * w.z; a1[3] += h1v * w.w;
        }
        float4 bv = *(const float4*)&bias2[g * FEAT + nc * 64 + cg * 4];
        float r0[4], r1[4];
        r0[0] = fmaxf(a0[0] + bv.x, 0.f); r0[1] = fmaxf(a0[1] + bv.y, 0.f);
        r0[2] = fmaxf(a0[2] + bv.z, 0.f); r0[3] = fmaxf(a0[3] + bv.w, 0.f);
        r1[0] = fmaxf(a1[0] + bv.x, 0.f); r1[1] = fmaxf(a1[1] + bv.y, 0.f);
        r1[2] = fmaxf(a1[2] + bv.z, 0.f); r1[3] = fmaxf(a1[3] + bv.w, 0.f);
        int row0 = rowBase + rg * 2;
        *(float4*)&rout[(size_t)row0 * FEAT + nc * 64 + cg * 4] =
            make_float4(r0[0], r0[1], r0[2], r0[3]);
        *(float4*)&rout[(size_t)(row0 + 1) * FEAT + nc * 64 + cg * 4] =
            make_float4(r1[0], r1[1], r1[2], r1[3]);
        float s4[4], q4[4];
#pragma unroll
        for (int j = 0; j < 4; ++j) {
            s4[j] = r0[j] + r1[j];
            q4[j] = r0[j] * r0[j] + r1[j] * r1[j];
        }
#pragma unroll
        for (int j = 0; j < 4; ++j) {
            s4[j] += __shfl_xor(s4[j], 16); q4[j] += __shfl_xor(q4[j], 16);
            s4[j] += __shfl_xor(s4[j], 32); q4[j] += __shfl_xor(q4[j], 32);
        }
        if (lane < 16) {
#pragma unroll
            for (int j = 0; j < 4; ++j) {
                smS[wvid][lane * 4 + j] = s4[j];
                smQ[wvid][lane * 4 + j] = q4[j];
            }
        }
        __syncthreads();
        if (tid < 64) {
            float ss = smS[0][tid] + smS[1][tid] + smS[2][tid] + smS[3][tid];
            float qq = smQ[0][tid] + smQ[1][tid] + smQ[2][tid] + smQ[3][tid];
            psum[(size_t)(nc * 64 + tid) * 1024 + b] = ss;
            psq [(size_t)(nc * 64 + tid) * 1024 + b] = qq;
        }
    }
}

// ===== 8. BN scale/shift from per-block partials (transposed [col][block]) =====
__global__ void bnst2_k(const float* __restrict__ psum, const float* __restrict__ psq,
                        const float* __restrict__ gamma, const float* __restrict__ beta,
                        float* __restrict__ scsh) {
    __shared__ float wS[4], wQ[4];
    const int c = blockIdx.x;
    const int tid = threadIdx.x;
    float s = psum[(size_t)c * 1024 + tid] + psum[(size_t)c * 1024 + 256 + tid]
            + psum[(size_t)c * 1024 + 512 + tid] + psum[(size_t)c * 1024 + 768 + tid];
    float q = psq[(size_t)c * 1024 + tid] + psq[(size_t)c * 1024 + 256 + tid]
            + psq[(size_t)c * 1024 + 512 + tid] + psq[(size_t)c * 1024 + 768 + tid];
#pragma unroll
    for (int m = 1; m <= 32; m <<= 1) { s += __shfl_xor(s, m); q += __shfl_xor(q, m); }
    if ((tid & 63) == 0) { wS[tid >> 6] = s; wQ[tid >> 6] = q; }
    __syncthreads();
    if (tid == 0) {
        float S = wS[0] + wS[1] + wS[2] + wS[3];
        float Q = wQ[0] + wQ[1] + wQ[2] + wQ[3];
        float mu = S * (1.0f / (float)NN);
        float var = Q * (1.0f / (float)NN) - mu * mu;
        float sc = gamma[c] * rsqrtf(var + 1e-5f);
        scsh[c] = sc;
        scsh[FEAT + c] = beta[c] - mu * sc;
    }
}

// ================= 9. out = x + r*scale + shift (in-place on d_out) =================
__global__ void final_k(const float* __restrict__ x, const float* __restrict__ scsh,
                        float* __restrict__ out) {
    const int total4 = NN * (FEAT / 4);
    for (int idx = blockIdx.x * 256 + threadIdx.x; idx < total4; idx += 2048 * 256) {
        int col4 = idx & (FEAT / 4 - 1);
        float4 rv = *(float4*)&out[(size_t)idx * 4];
        float4 xv = *(const float4*)&x[(size_t)idx * 4];
        float4 sc = *(const float4*)&scsh[col4 * 4];
        float4 sh = *(const float4*)&scsh[FEAT + col4 * 4];
        float4 o = { xv.x + rv.x * sc.x + sh.x, xv.y + rv.y * sc.y + sh.y,
                     xv.z + rv.z * sc.z + sh.z, xv.w + rv.w * sc.w + sh.w };
        *(float4*)&out[(size_t)idx * 4] = o;
    }
}

// =============================== launcher ===============================
extern "C" void kernel_launch(void* const* d_in, const int* in_sizes, int n_in,
                              void* d_out, int out_size, void* d_ws, size_t ws_size,
                              hipStream_t stream) {
    const float* x     = (const float*)d_in[0];
    const int*   ei    = (const int*)d_in[1];
    const float* W1    = (const float*)d_in[5];
    const float* b1    = (const float*)d_in[6];
    const float* W2    = (const float*)d_in[7];
    const float* b2    = (const float*)d_in[8];
    const float* W_in  = (const float*)d_in[9];
    const float* b_in  = (const float*)d_in[10];
    const float* g1W   = (const float*)d_in[11];
    const float* g1b   = (const float*)d_in[12];
    const float* l1W   = (const float*)d_in[13];
    const float* g2W   = (const float*)d_in[14];
    const float* g2b   = (const float*)d_in[15];
    const float* l2W   = (const float*)d_in[16];
    const float* gamma = (const float*)d_in[17];
    const float* beta  = (const float*)d_in[18];
    float* out = (float*)d_out;
    float* ws  = (float*)d_ws;

    float* fv    = ws;                 // [0, 262144)
    float* dvT   = ws + 262144;        // [262144, 524288)  (col-major [8][N])
    float* h0    = ws + 524288;        // [524288, 2621440)
    float* h1    = ws + 2621440;       // [2621440, 4718592)
    unsigned short* W1hi = (unsigned short*)(ws + 262144);  // aliases dvT (written later)
    unsigned short* W1lo = (unsigned short*)(ws + 393216);
    float*        fvpart = ws + 524288;                     // aliases h0 (dead after fvred)
    float*        fvT  = ws + 2621440;                      // aliases h1 (written later)
    unsigned int* suvw = (unsigned int*)(ws + 2883584);
    float* psum  = ws + 524288;        // aliases h0 (dead after ds1)
    float* psq   = ws + 1048576;
    float* bias1 = ws + 4720640;
    float* bias2 = ws + 4724736;
    float* scsh  = ws + 5003264;

    hipLaunchKernelGGL(w1swz_k,    dim3(64),   dim3(256), 0, stream, W1, W1hi, W1lo);
    hipLaunchKernelGGL(mfma_fv_k,  dim3(1024), dim3(256), 0, stream, x, W1hi, W1lo, b1, W2, fvpart);
    hipLaunchKernelGGL(fvred_k,    dim3(128),  dim3(256), 0, stream, fvpart, b2, fv, fvT);
    hipLaunchKernelGGL(uf_sort_k,  dim3(256),  dim3(512), 0, stream, fvT, ei, suvw);
    hipLaunchKernelGGL(uf_merge_k, dim3(256),  dim3(256), 0, stream, fvT, suvw, dvT);
    hipLaunchKernelGGL(feat_k,     dim3(128),  dim3(256), 0, stream, fv, dvT, W_in, b_in, h0);
    hipLaunchKernelGGL(redlam_k,   dim3(32),   dim3(256), 0, stream, h0, l1W, g1b, bias1, 64);
    hipLaunchKernelGGL(ds1_k,      dim3(128),  dim3(256), 0, stream, h0, g1W, bias1, h1);
    hipLaunchKernelGGL(redlam_k,   dim3(32),   dim3(256), 0, stream, h1, l2W, g2b, bias2, 512);
    hipLaunchKernelGGL(ds2_k,      dim3(1024), dim3(256), 0, stream, h1, g2W, bias2, out, psum, psq);
    hipLaunchKernelGGL(bnst2_k,    dim3(512),  dim3(256), 0, stream, psum, psq, gamma, beta, scsh);
    hipLaunchKernelGGL(final_k,    dim3(2048), dim3(256), 0, stream, x, scsh, out);
}